// Round 16
// baseline (701.663 us; speedup 1.0000x reference)
//
#include <hip/hip_runtime.h>

#define Nn   50000
#define Ee   400000
#define Ff   512
#define H1   1024
#define H2   512
#define Bb   50
#define OUTd 10
#define EPSc 1e-5f
#define NPg  1000   // nodes per graph
#define EPg  8000   // edges per graph

typedef _Float16 h8 __attribute__((ext_vector_type(8)));
typedef _Float16 h4 __attribute__((ext_vector_type(4)));
typedef float f4 __attribute__((ext_vector_type(4)));

// ---------- monotone float<->uint mapping for atomicMax on floats ----------
__device__ __forceinline__ unsigned fmap(float f) {
    unsigned u = __float_as_uint(f);
    return (u & 0x80000000u) ? ~u : (u | 0x80000000u);
}
__device__ __forceinline__ float funmap(unsigned m) {
    unsigned u = (m & 0x80000000u) ? (m ^ 0x80000000u) : ~m;
    return __uint_as_float(u);
}

__device__ __forceinline__ void gl_lds16(const void* g, void* l) {
    __builtin_amdgcn_global_load_lds(
        (const __attribute__((address_space(1))) unsigned int*)g,
        (__attribute__((address_space(3))) unsigned int*)l,
        16, 0, 0);
}

// ---------- fused prep: zero accumulators + split x, split W1, convert W2 ----------
__global__ void prep_kernel(const float* __restrict__ x, _Float16* __restrict__ xhi, _Float16* __restrict__ xlo,
                            const float* __restrict__ W1, _Float16* __restrict__ w1h, _Float16* __restrict__ w1l,
                            const float* __restrict__ W2, _Float16* __restrict__ w2h,
                            double* __restrict__ cs1, double* __restrict__ css1,
                            double* __restrict__ cs2, double* __restrict__ css2, int* __restrict__ scal) {
    int i = blockIdx.x * blockDim.x + threadIdx.x;
    int nth = gridDim.x * blockDim.x;
    for (int j = i; j < H1; j += nth) { cs1[j] = 0.0; css1[j] = 0.0; }
    for (int j = i; j < H2; j += nth) { cs2[j] = 0.0; css2[j] = 0.0; }
    if (i < 16) scal[i] = 0;
    const int nx = Nn * Ff / 4, nw1 = H1 * Ff / 4, nw2 = H2 * H1 / 4;
    for (int k = i; k < nx; k += nth) {
        float4 v = ((const float4*)x)[k];
        h4 H = { (_Float16)v.x, (_Float16)v.y, (_Float16)v.z, (_Float16)v.w };
        h4 L = { (_Float16)(v.x - (float)H[0]), (_Float16)(v.y - (float)H[1]),
                 (_Float16)(v.z - (float)H[2]), (_Float16)(v.w - (float)H[3]) };
        ((h4*)xhi)[k] = H;
        ((h4*)xlo)[k] = L;
    }
    for (int k = i; k < nw1; k += nth) {
        float4 v = ((const float4*)W1)[k];
        h4 H = { (_Float16)v.x, (_Float16)v.y, (_Float16)v.z, (_Float16)v.w };
        h4 L = { (_Float16)(v.x - (float)H[0]), (_Float16)(v.y - (float)H[1]),
                 (_Float16)(v.z - (float)H[2]), (_Float16)(v.w - (float)H[3]) };
        ((h4*)w1h)[k] = H;
        ((h4*)w1l)[k] = L;
    }
    for (int k = i; k < nw2; k += nth) {
        float4 v = ((const float4*)W2)[k];
        h4 H = { (_Float16)v.x, (_Float16)v.y, (_Float16)v.z, (_Float16)v.w };
        ((h4*)w2h)[k] = H;
    }
}

// ---------- GEMM1: 128x128 SPLIT tile, BK=32, 4 waves, SINGLE-buffered LDS (32KB),
// 2 barriers per K-step (m97 structure): STAGE -> sync(drain) -> compute -> sync.
// 152 regs/wave -> 3 waves/SIMD; 32KB LDS -> 3 blocks/CU resident: cross-block
// wave overlap covers the barrier drains (m114). XCD-chunk + granule swizzle.
// C = Ahi*Bhi + Ahi*Blo + Alo*Bhi — per-element FP chain identical -> bit-identical h.
__global__ __launch_bounds__(256) void gemm1_mfma_kernel(
        const _Float16* __restrict__ Ahi, const _Float16* __restrict__ Alo,
        const _Float16* __restrict__ Bhi, const _Float16* __restrict__ Blo,
        const float* __restrict__ bias, float* __restrict__ C,
        double* __restrict__ csum, double* __restrict__ cssum)
{
    const int M = Nn;
    const int nwg = gridDim.x, orig = blockIdx.x;
    const int qq = nwg >> 3, rr = nwg & 7;
    const int xcd = orig & 7, idx = orig >> 3;
    const int lin = (xcd < rr ? xcd * (qq + 1) : rr * (qq + 1) + (xcd - rr) * qq) + idx;
    const int nT = H1 / 128;               // 8, n-fastest
    const int bmI = lin / nT;
    const int bm = bmI * 128, bn = (lin - bmI * nT) * 128;
    if (bm >= M) return;
    __shared__ __align__(16) _Float16 smem[4][128 * 32];   // 32 KB single buffer
    const int tid = threadIdx.x, lane = tid & 63, wave = tid >> 6;
    const int rIn = lane >> 2;
    const int kSrcByte = ((((lane & 3) - ((lane >> 3) & 3)) & 3) << 4);
    const int wr = wave >> 1, wc = wave & 1;
    const int lr = lane & 15, kb = lane >> 4;
    const int pGr = ((kb + ((lr >> 1) & 3)) & 3) << 3;
    f4 acc[4][4] = {};

    const _Float16* gp = (wave == 0) ? Ahi : (wave == 1) ? Alo : (wave == 2) ? Bhi : Blo;
    const bool isA = (wave < 2);
    const int tb = isA ? bm : bn;

    for (int k0 = 0; k0 < Ff; k0 += 32) {
        // stage this K-tile into the single buffer
        {
            _Float16* lp = smem[wave];
#pragma unroll
            for (int c = 0; c < 8; ++c) {
                int row = tb + c * 16 + rIn;
                if (isA) row = min(row, M - 1);
                gl_lds16((const char*)gp + ((size_t)row * Ff + k0) * 2 + kSrcByte, lp + c * 512);
            }
        }
        __syncthreads();                   // staging drained (vmcnt0 in syncthreads)
        const _Float16* AhP = smem[0];
        const _Float16* AlP = smem[1];
        const _Float16* BhP = smem[2];
        const _Float16* BlP = smem[3];
        const int ar = (wr * 64 + lr) * 32 + pGr;
        const int br = (wc * 64 + lr) * 32 + pGr;
        h8 ahf[4], bhf[4], alf[4], blf[4];
#pragma unroll
        for (int i = 0; i < 4; ++i) {
            ahf[i] = *(const h8*)&AhP[ar + i * 512];
            bhf[i] = *(const h8*)&BhP[br + i * 512];
            alf[i] = *(const h8*)&AlP[ar + i * 512];
            blf[i] = *(const h8*)&BlP[br + i * 512];
        }
#pragma unroll
        for (int mi = 0; mi < 4; ++mi)
#pragma unroll
            for (int ni = 0; ni < 4; ++ni) {
                acc[mi][ni] = __builtin_amdgcn_mfma_f32_16x16x32_f16(ahf[mi], bhf[ni], acc[mi][ni], 0, 0, 0);
                acc[mi][ni] = __builtin_amdgcn_mfma_f32_16x16x32_f16(ahf[mi], blf[ni], acc[mi][ni], 0, 0, 0);
                acc[mi][ni] = __builtin_amdgcn_mfma_f32_16x16x32_f16(alf[mi], bhf[ni], acc[mi][ni], 0, 0, 0);
            }
        __syncthreads();                   // reads done before next-step overwrite
    }
    // epilogue: bias, store, fused column stats. C/D map: col=lane&15, row=(lane>>4)*4+reg
#pragma unroll
    for (int ni = 0; ni < 4; ++ni) {
        const int col = bn + wc * 64 + ni * 16 + lr;
        const float bv = bias[col];
        double sd_ = 0.0, ssd = 0.0;
#pragma unroll
        for (int mi = 0; mi < 4; ++mi)
#pragma unroll
            for (int r = 0; r < 4; ++r) {
                int row = bm + wr * 64 + mi * 16 + kb * 4 + r;
                if (row < M) {
                    float v = acc[mi][ni][r] + bv;
                    C[(size_t)row * H1 + col] = v;
                    sd_ += (double)v;
                    ssd += (double)v * (double)v;
                }
            }
        sd_ += __shfl_xor(sd_, 16); ssd += __shfl_xor(ssd, 16);
        sd_ += __shfl_xor(sd_, 32); ssd += __shfl_xor(ssd, 32);
        if (kb == 0) {
            atomicAdd(&csum[col], sd_);
            atomicAdd(&cssum[col], ssd);
        }
    }
}

// ---------- GEMM2: 128x128 non-split (round-7 proven schedule, dbuf LDS staging) ----------
__global__ __launch_bounds__(256) void gemm2_kernel(
        const _Float16* __restrict__ Ag, const _Float16* __restrict__ Bh,
        const float* __restrict__ bias, float* __restrict__ C,
        const int* __restrict__ Mptr, int nT,
        double* __restrict__ csum, double* __restrict__ cssum)
{
    const int M = Mptr[0];
    const int nwg = gridDim.x, orig = blockIdx.x;
    const int qq = nwg >> 3, rr = nwg & 7;
    const int xcd = orig & 7, idx = orig >> 3;
    const int lin = (xcd < rr ? xcd * (qq + 1) : rr * (qq + 1) + (xcd - rr) * qq) + idx;
    const int bmI = lin / nT;
    const int bm = bmI * 128, bn = (lin - bmI * nT) * 128;
    if (bm >= M) return;
    __shared__ __align__(16) _Float16 smem[2][2][128 * 32];
    const int tid = threadIdx.x, lane = tid & 63, wave = tid >> 6;
    const int rIn = lane >> 2;
    const int kSrcByte = ((((lane & 3) - ((lane >> 3) & 3)) & 3) << 4);
    const int wr = wave >> 1, wc = wave & 1;
    const int lr = lane & 15, kb = lane >> 4;
    const int pGr = ((kb + ((lr >> 1) & 3)) & 3) << 3;
    f4 acc[4][4] = {};

    auto STAGE = [&](int b, int k0) {
        const bool isA = (wave < 2);
        const _Float16* gp = isA ? Ag : Bh;
        _Float16* lp = smem[b][isA ? 0 : 1];
        const int tb = isA ? bm : bn;
        const int hf = wave & 1;
#pragma unroll
        for (int c2 = 0; c2 < 4; ++c2) {
            int c = hf * 4 + c2;
            int row = tb + c * 16 + rIn;
            if (isA) row = min(row, M - 1);
            gl_lds16((const char*)gp + ((size_t)row * H1 + k0) * 2 + kSrcByte, lp + c * 512);
        }
    };

    int cur = 0;
    STAGE(0, 0);
    for (int k0 = 0; k0 < H1; k0 += 32) {
        __syncthreads();
        if (k0 + 32 < H1) STAGE(cur ^ 1, k0 + 32);
        const _Float16* AhP = smem[cur][0];
        const _Float16* BhP = smem[cur][1];
        const int ar = (wr * 64 + lr) * 32 + pGr;
        const int br = (wc * 64 + lr) * 32 + pGr;
        h8 ahf[4], bhf[4];
#pragma unroll
        for (int i = 0; i < 4; ++i) {
            ahf[i] = *(const h8*)&AhP[ar + i * 512];
            bhf[i] = *(const h8*)&BhP[br + i * 512];
        }
#pragma unroll
        for (int mi = 0; mi < 4; ++mi)
#pragma unroll
            for (int ni = 0; ni < 4; ++ni)
                acc[mi][ni] = __builtin_amdgcn_mfma_f32_16x16x32_f16(ahf[mi], bhf[ni], acc[mi][ni], 0, 0, 0);
        cur ^= 1;
    }
#pragma unroll
    for (int ni = 0; ni < 4; ++ni) {
        const int col = bn + wc * 64 + ni * 16 + lr;
        const float bv = bias[col];
        double sd_ = 0.0, ssd = 0.0;
#pragma unroll
        for (int mi = 0; mi < 4; ++mi)
#pragma unroll
            for (int r = 0; r < 4; ++r) {
                int row = bm + wr * 64 + mi * 16 + kb * 4 + r;
                if (row < M) {
                    float v = acc[mi][ni][r] + bv;
                    C[(size_t)row * H2 + col] = v;
                    sd_ += (double)v;
                    ssd += (double)v * (double)v;
                }
            }
        sd_ += __shfl_xor(sd_, 16); ssd += __shfl_xor(ssd, 16);
        sd_ += __shfl_xor(sd_, 32); ssd += __shfl_xor(ssd, 32);
        if (kb == 0) {
            atomicAdd(&csum[col], sd_);
            atomicAdd(&cssum[col], ssd);
        }
    }
}

// ---------- BN params ----------
__global__ void bnparam_kernel(const double* __restrict__ s, const double* __restrict__ ss,
                               const float* __restrict__ g, const float* __restrict__ be,
                               float* __restrict__ a, float* __restrict__ bb, int cols,
                               const float* __restrict__ padBias, const int* __restrict__ CvPtr) {
    int j = blockIdx.x * blockDim.x + threadIdx.x;
    if (j >= cols) return;
    double sum = s[j], sumsq = ss[j];
    if (CvPtr) {
        double pad = (double)(Nn - CvPtr[0]);
        double bv = padBias ? (double)padBias[j] : 0.0;
        sum += pad * bv; sumsq += pad * bv * bv;
    }
    double mean = sum / (double)Nn;
    double var = sumsq / (double)Nn - mean * mean;
    float aj = g[j] / sqrtf((float)var + EPSc);
    a[j] = aj;
    bb[j] = be[j] - (float)mean * aj;
}

// ---------- p,q row dots over BN+ReLU(h), no write-back; one WAVE per node ----------
__global__ __launch_bounds__(256) void pq_kernel(const float* __restrict__ h,
        const float* __restrict__ a, const float* __restrict__ bb,
        const float* __restrict__ Wp, float* __restrict__ p, float* __restrict__ q) {
    const int n = blockIdx.x * 4 + (threadIdx.x >> 6);
    if (n >= Nn) return;
    const int lane = threadIdx.x & 63;
    float sp = 0.f, sq = 0.f;
    const float* row = h + (size_t)n * H1;
#pragma unroll
    for (int u = 0; u < 4; ++u) {
        int j = u * 256 + lane * 4;
        float4 v = *(const float4*)(row + j);
        const float4 av = *(const float4*)(a + j);
        const float4 bv = *(const float4*)(bb + j);
        v.x = fmaxf(v.x * av.x + bv.x, 0.f);
        v.y = fmaxf(v.y * av.y + bv.y, 0.f);
        v.z = fmaxf(v.z * av.z + bv.z, 0.f);
        v.w = fmaxf(v.w * av.w + bv.w, 0.f);
        const float4 wp = *(const float4*)(Wp + j);
        const float4 wq = *(const float4*)(Wp + H1 + j);
        sp += v.x * wp.x + v.y * wp.y + v.z * wp.z + v.w * wp.w;
        sq += v.x * wq.x + v.y * wq.y + v.z * wq.z + v.w * wq.w;
    }
#pragma unroll
    for (int off = 32; off > 0; off >>= 1) {
        sp += __shfl_xor(sp, off);
        sq += __shfl_xor(sq, off);
    }
    if (lane == 0) { p[n] = sp; q[n] = sq; }
}

// ---------- fused edge-score + greedy matching, one block per graph ----------
__global__ __launch_bounds__(1024) void match_fused_kernel(
        const int* __restrict__ ei,
        const float* __restrict__ p, const float* __restrict__ q,
        const float* __restrict__ bp,
        unsigned long long* __restrict__ packed,
        int* __restrict__ nodeA, int* __restrict__ nodeB,
        float* __restrict__ multc, int* __restrict__ scal,
        int* __restrict__ gbase, int* __restrict__ gcnt) {
    __shared__ __align__(16) char LB[52096];
    unsigned short* lst = (unsigned short*)LB;            // [2][8000]
    float* earr = (float*)LB;
    float* pl = (float*)(LB + 32000);
    float* ql = pl + NPg;
    unsigned long long* best = (unsigned long long*)(LB + 32000);
    unsigned* maxu = (unsigned*)(LB + 40000);
    int* mergedS = (int*)(LB + 40000);
    unsigned long long* den = (unsigned long long*)(LB + 44000);
    float* lmult = (float*)(LB + 44000);
    unsigned short* lsA = (unsigned short*)(LB + 48000);
    unsigned short* ldA = (unsigned short*)(LB + 50000);
    int* cnts = (int*)(LB + 52032);

    const int g = blockIdx.x;
    const int tid = threadIdx.x;
    const int e0 = g * EPg, n0 = g * NPg;
    const int* srcp = ei + e0;
    const int* dstp = ei + Ee + e0;
    const float bpv = bp[0];

    for (int i = tid; i < NPg; i += 1024) {
        pl[i] = p[n0 + i];
        ql[i] = q[n0 + i];
        maxu[i] = 0u;
        den[i] = 0ull;
    }
    __syncthreads();
    for (int i = tid; i < EPg; i += 1024) {
        int s = srcp[i] - n0, d = dstp[i] - n0;
        float e = pl[s] + ql[d] + bpv;
        earr[i] = e;
        atomicMax(&maxu[d], fmap(e));
    }
    __syncthreads();
    for (int i = tid; i < EPg; i += 1024) {
        int d = dstp[i] - n0;
        float ex = expf(earr[i] - funmap(maxu[d]));
        atomicAdd(&den[d], (unsigned long long)(ex * 4294967296.0f));
    }
    __syncthreads();
    for (int i = tid; i < EPg; i += 1024) {
        int s = srcp[i] - n0, d = dstp[i] - n0;
        float ex = expf(earr[i] - funmap(maxu[d]));
        float den_f = (float)((double)den[d] * (1.0 / 4294967296.0));
        float sc = ex / den_f + 0.5f;
        packed[e0 + i] = ((unsigned long long)__float_as_uint(sc) << 33)
                       | ((unsigned long long)(8191u - (unsigned)i) << 20)
                       | ((unsigned long long)(unsigned)s << 10) | (unsigned long long)(unsigned)d;
    }
    __syncthreads();
    for (int i = tid; i < NPg; i += 1024) mergedS[i] = 0;
    for (int i = tid; i < EPg; i += 1024) lst[i] = (unsigned short)i;
    if (tid == 0) { cnts[0] = EPg; cnts[1] = 0; cnts[2] = 0; }
    __syncthreads();
    int cur = 0;
    for (int round = 0; round < 20000; ++round) {
        const int n_cur = cnts[cur];
        if (n_cur == 0) break;
        if (tid == 0) cnts[cur ^ 1] = 0;
        for (int i = tid; i < NPg; i += 1024) best[i] = 0ull;
        __syncthreads();
        for (int ii = tid; ii < n_cur; ii += 1024) {
            int le = lst[cur * EPg + ii];
            unsigned long long pk = packed[e0 + le];
            int s = (int)((pk >> 10) & 1023), d = (int)(pk & 1023);
            if (mergedS[s] | mergedS[d]) { lst[cur * EPg + ii] = 0xFFFF; continue; }
            atomicMax(&best[s], pk);
            atomicMax(&best[d], pk);
        }
        __syncthreads();
        for (int ii = tid; ii < n_cur; ii += 1024) {
            int le = lst[cur * EPg + ii];
            if (le == 0xFFFF) continue;
            unsigned long long pk = packed[e0 + le];
            int s = (int)((pk >> 10) & 1023), d = (int)(pk & 1023);
            if (best[s] == pk && best[d] == pk) {
                int c = atomicAdd(&cnts[2], 1);
                lsA[c] = (unsigned short)s;
                ldA[c] = (s == d) ? (unsigned short)0xFFFF : (unsigned short)d;
                lmult[c] = __uint_as_float((unsigned)(pk >> 33));
                mergedS[s] = 1;
                if (d != s) mergedS[d] = 1;
            } else {
                int pos = atomicAdd(&cnts[cur ^ 1], 1);
                lst[(cur ^ 1) * EPg + pos] = (unsigned short)le;
            }
        }
        __syncthreads();
        cur ^= 1;
    }
    for (int i = tid; i < NPg; i += 1024) {
        if (!mergedS[i]) {
            int c = atomicAdd(&cnts[2], 1);
            lsA[c] = (unsigned short)i;
            ldA[c] = 0xFFFF;
            lmult[c] = 1.0f;
        }
    }
    __syncthreads();
    if (tid == 0) {
        int ncl = cnts[2];
        int base = atomicAdd(&scal[2], ncl);
        cnts[3] = base;
        gbase[g] = base;
        gcnt[g] = ncl;
    }
    __syncthreads();
    const int ncl = cnts[2], base = cnts[3];
    for (int i = tid; i < ncl; i += 1024) {
        nodeA[base + i] = n0 + (int)lsA[i];
        nodeB[base + i] = (ldA[i] == 0xFFFF) ? -1 : (n0 + (int)ldA[i]);
        multc[base + i] = lmult[i];
    }
}

// ---------- gather clustered rows: Ag[c] = f16(mult*(relu(bn(h[a]))+relu(bn(h[b])))) ----------
__global__ __launch_bounds__(256) void gather_kernel(const float* __restrict__ h,
        const float* __restrict__ a, const float* __restrict__ bb,
        const int* __restrict__ nodeA, const int* __restrict__ nodeB,
        const float* __restrict__ multc, const int* __restrict__ scal,
        _Float16* __restrict__ Ag) {
    int c = blockIdx.x * 4 + (threadIdx.x >> 6);
    if (c >= scal[2]) return;
    const int lane = threadIdx.x & 63;
    int na = nodeA[c], nb = nodeB[c];
    float mu = multc[c];
#pragma unroll
    for (int u = 0; u < 4; ++u) {
        int j = u * 256 + lane * 4;
        const float4 av = *(const float4*)(a + j);
        const float4 bv = *(const float4*)(bb + j);
        float4 v = *(const float4*)(h + (size_t)na * H1 + j);
        v.x = fmaxf(v.x * av.x + bv.x, 0.f);
        v.y = fmaxf(v.y * av.y + bv.y, 0.f);
        v.z = fmaxf(v.z * av.z + bv.z, 0.f);
        v.w = fmaxf(v.w * av.w + bv.w, 0.f);
        if (nb >= 0) {
            float4 w = *(const float4*)(h + (size_t)nb * H1 + j);
            v.x += fmaxf(w.x * av.x + bv.x, 0.f);
            v.y += fmaxf(w.y * av.y + bv.y, 0.f);
            v.z += fmaxf(w.z * av.z + bv.z, 0.f);
            v.w += fmaxf(w.w * av.w + bv.w, 0.f);
        }
        h4 o = { (_Float16)(mu * v.x), (_Float16)(mu * v.y), (_Float16)(mu * v.z), (_Float16)(mu * v.w) };
        *(h4*)(Ag + (size_t)c * H1 + j) = o;
    }
}

// ---------- BN2+ReLU+per-graph sum pool over contiguous segments (no atomics) ----------
__global__ __launch_bounds__(256) void pool_seg_kernel(const float* __restrict__ C2,
        const float* __restrict__ a2, const float* __restrict__ bb2,
        const int* __restrict__ gbase, const int* __restrict__ gcnt,
        float* __restrict__ pool) {
    const int g = blockIdx.x;
    const int j = blockIdx.y * 256 + threadIdx.x;
    const int b0 = gbase[g], cN = gcnt[g];
    const float aj = a2[j], bj = bb2[j];
    float s = 0.f;
    for (int c = b0; c < b0 + cN; ++c)
        s += fmaxf(C2[(size_t)c * H2 + j] * aj + bj, 0.f);
    pool[g * H2 + j] = s;
}

// ---------- FC layers ----------
__global__ void fc1_kernel(const float* __restrict__ pool, const int* __restrict__ gcnt,
                           const float* __restrict__ Wfc, const float* __restrict__ bfc,
                           float* __restrict__ hid) {
    int g = blockIdx.x;
    int o = threadIdx.x;
    float inv = 1.0f / fmaxf((float)gcnt[g], 1.0f);
    if (o < 200) {
        float s = 0.f;
        for (int j = 0; j < H2; ++j) s += (pool[g * H2 + j] * inv) * Wfc[o * H2 + j];
        hid[g * 200 + o] = fmaxf(s + bfc[o], 0.f);
    }
}
__global__ void fc2_kernel(const float* __restrict__ hid, const float* __restrict__ Wfc1,
                           const float* __restrict__ bfc1, float* __restrict__ out) {
    int idx = threadIdx.x;
    if (idx < Bb * OUTd) {
        int g = idx / OUTd, o = idx % OUTd;
        float s = bfc1[o];
        for (int t = 0; t < 200; ++t) s += hid[g * 200 + t] * Wfc1[o * 200 + t];
        out[idx] = s;
    }
}

extern "C" void kernel_launch(void* const* d_in, const int* in_sizes, int n_in,
                              void* d_out, int out_size, void* d_ws, size_t ws_size,
                              hipStream_t stream) {
    (void)in_sizes; (void)n_in; (void)out_size; (void)ws_size;
    const float* x    = (const float*)d_in[0];
    const int*   ei   = (const int*)d_in[1];
    const float* W1   = (const float*)d_in[3];
    const float* b1   = (const float*)d_in[4];
    const float* g1   = (const float*)d_in[5];
    const float* be1  = (const float*)d_in[6];
    const float* Wp   = (const float*)d_in[7];
    const float* bp   = (const float*)d_in[8];
    const float* W2   = (const float*)d_in[9];
    const float* b2   = (const float*)d_in[10];
    const float* g2   = (const float*)d_in[11];
    const float* be2  = (const float*)d_in[12];
    const float* Wfc  = (const float*)d_in[13];
    const float* bfc  = (const float*)d_in[14];
    const float* Wfc1 = (const float*)d_in[15];
    const float* bfc1 = (const float*)d_in[16];

    char* w = (char*)d_ws;
    auto take = [&](size_t bytes) -> char* {
        char* r = w;
        w += (bytes + 255) & ~(size_t)255;
        return r;
    };
    // R1: h (f32) -> reused as gemm2 output C2 after gather
    float* h      = (float*)take((size_t)Nn * H1 * 4);          // 204.8 MB
    // R2: xhi|xlo -> reused as Ag (f16 gathered rows) after matching
    _Float16* xhi = (_Float16*)take((size_t)Nn * Ff * 2);       // 51.2 MB
    _Float16* xlo = (_Float16*)take((size_t)Nn * Ff * 2);       // 51.2 MB
    _Float16* w1h = (_Float16*)take((size_t)H1 * Ff * 2);
    _Float16* w1l = (_Float16*)take((size_t)H1 * Ff * 2);
    _Float16* w2h = (_Float16*)take((size_t)H2 * H1 * 2);
    float* p      = (float*)take((size_t)Nn * 4);
    float* q      = (float*)take((size_t)Nn * 4);
    unsigned long long* packed = (unsigned long long*)take((size_t)Ee * 8);
    int* nodeA    = (int*)take((size_t)Nn * 4);
    int* nodeB    = (int*)take((size_t)Nn * 4);
    float* multc  = (float*)take((size_t)Nn * 4);
    double* cs1   = (double*)take((size_t)H1 * 8);
    double* css1  = (double*)take((size_t)H1 * 8);
    double* cs2   = (double*)take((size_t)H2 * 8);
    double* css2  = (double*)take((size_t)H2 * 8);
    float* a1     = (float*)take((size_t)H1 * 4);
    float* bb1    = (float*)take((size_t)H1 * 4);
    float* a2     = (float*)take((size_t)H2 * 4);
    float* bb2    = (float*)take((size_t)H2 * 4);
    float* pool   = (float*)take((size_t)Bb * H2 * 4);
    float* hid    = (float*)take((size_t)Bb * 200 * 4);
    int* scal     = (int*)take(64 * 4);
    int* gbase    = (int*)take(64 * 4);
    int* gcnt     = (int*)take(64 * 4);
    _Float16* Ag  = xhi;   // alias after gemm1
    float* C2o    = h;     // alias after gather

    const int mT  = (Nn + 127) / 128;   // 391

    prep_kernel<<<dim3(2048), dim3(256), 0, stream>>>(x, xhi, xlo, W1, w1h, w1l, W2, w2h,
                                                      cs1, css1, cs2, css2, scal);
    gemm1_mfma_kernel<<<dim3(mT * (H1 / 128)), dim3(256), 0, stream>>>(
        xhi, xlo, w1h, w1l, b1, h, cs1, css1);
    bnparam_kernel<<<dim3((H1 + 255) / 256), dim3(256), 0, stream>>>(cs1, css1, g1, be1, a1, bb1, H1, (const float*)nullptr, (const int*)nullptr);
    pq_kernel<<<dim3((Nn + 3) / 4), dim3(256), 0, stream>>>(h, a1, bb1, Wp, p, q);
    match_fused_kernel<<<dim3(Bb), dim3(1024), 0, stream>>>(ei, p, q, bp, packed,
        nodeA, nodeB, multc, scal, gbase, gcnt);
    gather_kernel<<<dim3((Nn + 3) / 4), dim3(256), 0, stream>>>(h, a1, bb1, nodeA, nodeB, multc, scal, Ag);
    gemm2_kernel<<<dim3(mT * (H2 / 128)), dim3(256), 0, stream>>>(
        Ag, w2h, b2, C2o, scal + 2, H2 / 128, cs2, css2);
    bnparam_kernel<<<dim3((H2 + 255) / 256), dim3(256), 0, stream>>>(cs2, css2, g2, be2, a2, bb2, H2, b2, scal + 2);
    pool_seg_kernel<<<dim3(Bb, H2 / 256), dim3(256), 0, stream>>>(C2o, a2, bb2, gbase, gcnt, pool);
    fc1_kernel<<<dim3(Bb), dim3(256), 0, stream>>>(pool, gcnt, Wfc, bfc, hid);
    fc2_kernel<<<dim3(1), dim3(512), 0, stream>>>(hid, Wfc1, bfc1, (float*)d_out);
}

// Round 17
// 680.177 us; speedup vs baseline: 1.0316x; 1.0316x over previous
//
#include <hip/hip_runtime.h>

#define Nn   50000
#define Ee   400000
#define Ff   512
#define H1   1024
#define H2   512
#define Bb   50
#define OUTd 10
#define EPSc 1e-5f
#define NPg  1000   // nodes per graph
#define EPg  8000   // edges per graph

typedef _Float16 h8 __attribute__((ext_vector_type(8)));
typedef _Float16 h4 __attribute__((ext_vector_type(4)));
typedef float f4 __attribute__((ext_vector_type(4)));

// ---------- monotone float<->uint mapping for atomicMax on floats ----------
__device__ __forceinline__ unsigned fmap(float f) {
    unsigned u = __float_as_uint(f);
    return (u & 0x80000000u) ? ~u : (u | 0x80000000u);
}
__device__ __forceinline__ float funmap(unsigned m) {
    unsigned u = (m & 0x80000000u) ? (m ^ 0x80000000u) : ~m;
    return __uint_as_float(u);
}

__device__ __forceinline__ void gl_lds16(const void* g, void* l) {
    __builtin_amdgcn_global_load_lds(
        (const __attribute__((address_space(1))) unsigned int*)g,
        (__attribute__((address_space(3))) unsigned int*)l,
        16, 0, 0);
}

// ---------- fused prep: zero accumulators + split x, split W1, convert W2 ----------
__global__ void prep_kernel(const float* __restrict__ x, _Float16* __restrict__ xhi, _Float16* __restrict__ xlo,
                            const float* __restrict__ W1, _Float16* __restrict__ w1h, _Float16* __restrict__ w1l,
                            const float* __restrict__ W2, _Float16* __restrict__ w2h,
                            double* __restrict__ cs1, double* __restrict__ css1,
                            double* __restrict__ cs2, double* __restrict__ css2, int* __restrict__ scal) {
    int i = blockIdx.x * blockDim.x + threadIdx.x;
    int nth = gridDim.x * blockDim.x;
    for (int j = i; j < H1; j += nth) { cs1[j] = 0.0; css1[j] = 0.0; }
    for (int j = i; j < H2; j += nth) { cs2[j] = 0.0; css2[j] = 0.0; }
    if (i < 16) scal[i] = 0;
    const int nx = Nn * Ff / 4, nw1 = H1 * Ff / 4, nw2 = H2 * H1 / 4;
    for (int k = i; k < nx; k += nth) {
        float4 v = ((const float4*)x)[k];
        h4 H = { (_Float16)v.x, (_Float16)v.y, (_Float16)v.z, (_Float16)v.w };
        h4 L = { (_Float16)(v.x - (float)H[0]), (_Float16)(v.y - (float)H[1]),
                 (_Float16)(v.z - (float)H[2]), (_Float16)(v.w - (float)H[3]) };
        ((h4*)xhi)[k] = H;
        ((h4*)xlo)[k] = L;
    }
    for (int k = i; k < nw1; k += nth) {
        float4 v = ((const float4*)W1)[k];
        h4 H = { (_Float16)v.x, (_Float16)v.y, (_Float16)v.z, (_Float16)v.w };
        h4 L = { (_Float16)(v.x - (float)H[0]), (_Float16)(v.y - (float)H[1]),
                 (_Float16)(v.z - (float)H[2]), (_Float16)(v.w - (float)H[3]) };
        ((h4*)w1h)[k] = H;
        ((h4*)w1l)[k] = L;
    }
    for (int k = i; k < nw2; k += nth) {
        float4 v = ((const float4*)W2)[k];
        h4 H = { (_Float16)v.x, (_Float16)v.y, (_Float16)v.z, (_Float16)v.w };
        ((h4*)w2h)[k] = H;
    }
}

// ---------- GEMM1: 256x256 SPLIT tile, BK=32, 8 waves (2Mx4N), 128 KB LDS dbuf,
// counted-vmcnt pipeline (T4, no vmcnt(0) drain in steady state):
//   B1(raw) -> STAGE(i+1) -> vmcnt(8) [stage(i) had full compute(i-1) in flight]
//   -> B2(raw) -> COMPUTE(i)
// Per-wave ledger: 8 gl_lds per STAGE; before wait outstanding={i,i+1}=16 ->
// vmcnt(8) retires stage(i) exactly. WAR on buf[(i+1)&1] covered by B1.
// XCD-chunk + granule swizzle. C = Ahi*Bhi + Ahi*Blo + Alo*Bhi (bit-identical h).
__global__ __launch_bounds__(512) void gemm1_256_kernel(
        const _Float16* __restrict__ Ahi, const _Float16* __restrict__ Alo,
        const _Float16* __restrict__ Bhi, const _Float16* __restrict__ Blo,
        const float* __restrict__ bias, float* __restrict__ C,
        double* __restrict__ csum, double* __restrict__ cssum)
{
    const int M = Nn;
    const int nwg = gridDim.x, orig = blockIdx.x;
    const int qq = nwg >> 3, rr = nwg & 7;
    const int xcd = orig & 7, idx = orig >> 3;
    const int lin = (xcd < rr ? xcd * (qq + 1) : rr * (qq + 1) + (xcd - rr) * qq) + idx;
    const int nT = H1 / 256;                   // 4
    const int bmI = lin / nT;
    const int bm = bmI * 256, bn = (lin - bmI * nT) * 256;
    __shared__ __align__(16) _Float16 smem[2][4][256 * 32];   // 128 KB
    const int tid = threadIdx.x, lane = tid & 63, wave = tid >> 6;   // 8 waves
    const int rIn = lane >> 2;
    const int kSrcByte = ((((lane & 3) - ((lane >> 3) & 3)) & 3) << 4);
    const int wr = wave >> 2, wc = wave & 3;   // wave grid 2(M) x 4(N)
    const int lr = lane & 15, kb = lane >> 4;
    const int pGr = ((kb + ((lr >> 1) & 3)) & 3) << 3;
    const int arr = wave >> 1;                 // 0=Ah 1=Al 2=Bh 3=Bl
    const int hv = wave & 1;                   // row half of the array
    const bool isA = (arr < 2);
    const _Float16* gp = (arr == 0) ? Ahi : (arr == 1) ? Alo : (arr == 2) ? Bhi : Blo;
    const int tb = isA ? bm : bn;
    f4 acc[8][4] = {};

    auto STAGE = [&](int b, int k0) {
        _Float16* lp = smem[b][arr] + hv * (128 * 32);
#pragma unroll
        for (int c = 0; c < 8; ++c) {
            int row = tb + hv * 128 + c * 16 + rIn;
            if (isA) row = min(row, M - 1);
            gl_lds16((const char*)gp + ((size_t)row * Ff + k0) * 2 + kSrcByte, lp + c * 512);
        }
    };

    int cur = 0;
    STAGE(0, 0);
    for (int k0 = 0; k0 < Ff; k0 += 32) {
        __builtin_amdgcn_sched_barrier(0);
        __builtin_amdgcn_s_barrier();                     // B1: compute(i-1) reads done
        __builtin_amdgcn_sched_barrier(0);
        if (k0 + 32 < Ff) {
            STAGE(cur ^ 1, k0 + 32);                      // issue next tile (WAR-safe after B1)
            asm volatile("s_waitcnt vmcnt(8)" ::: "memory");   // retire stage(i) only
        } else {
            asm volatile("s_waitcnt vmcnt(0)" ::: "memory");   // tail: retire last stage
        }
        __builtin_amdgcn_sched_barrier(0);
        __builtin_amdgcn_s_barrier();                     // B2: everyone's stage(i) landed
        __builtin_amdgcn_sched_barrier(0);
        const _Float16* AhP = smem[cur][0];
        const _Float16* AlP = smem[cur][1];
        const _Float16* BhP = smem[cur][2];
        const _Float16* BlP = smem[cur][3];
        h8 ahf[8], alf[8];
#pragma unroll
        for (int mi = 0; mi < 8; ++mi) {
            const int ar = (wr * 128 + mi * 16 + lr) * 32 + pGr;
            ahf[mi] = *(const h8*)&AhP[ar];
            alf[mi] = *(const h8*)&AlP[ar];
        }
#pragma unroll
        for (int ni = 0; ni < 4; ++ni) {
            const int br = (wc * 64 + ni * 16 + lr) * 32 + pGr;
            const h8 bh = *(const h8*)&BhP[br];
            const h8 bl = *(const h8*)&BlP[br];
#pragma unroll
            for (int mi = 0; mi < 8; ++mi) {
                acc[mi][ni] = __builtin_amdgcn_mfma_f32_16x16x32_f16(ahf[mi], bh, acc[mi][ni], 0, 0, 0);
                acc[mi][ni] = __builtin_amdgcn_mfma_f32_16x16x32_f16(ahf[mi], bl, acc[mi][ni], 0, 0, 0);
                acc[mi][ni] = __builtin_amdgcn_mfma_f32_16x16x32_f16(alf[mi], bh, acc[mi][ni], 0, 0, 0);
            }
        }
        cur ^= 1;
    }
    // epilogue: bias, store, fused column stats. C/D map: col=lane&15, row=(lane>>4)*4+reg
#pragma unroll
    for (int ni = 0; ni < 4; ++ni) {
        const int col = bn + wc * 64 + ni * 16 + lr;
        const float bv = bias[col];
        double sd_ = 0.0, ssd = 0.0;
#pragma unroll
        for (int mi = 0; mi < 8; ++mi)
#pragma unroll
            for (int r = 0; r < 4; ++r) {
                int row = bm + wr * 128 + mi * 16 + kb * 4 + r;
                if (row < M) {
                    float v = acc[mi][ni][r] + bv;
                    C[(size_t)row * H1 + col] = v;
                    sd_ += (double)v;
                    ssd += (double)v * (double)v;
                }
            }
        sd_ += __shfl_xor(sd_, 16); ssd += __shfl_xor(ssd, 16);
        sd_ += __shfl_xor(sd_, 32); ssd += __shfl_xor(ssd, 32);
        if (kb == 0) {
            atomicAdd(&csum[col], sd_);
            atomicAdd(&cssum[col], ssd);
        }
    }
}

// ---------- GEMM2: 128x128 non-split (round-7 proven schedule, dbuf LDS staging) ----------
__global__ __launch_bounds__(256) void gemm2_kernel(
        const _Float16* __restrict__ Ag, const _Float16* __restrict__ Bh,
        const float* __restrict__ bias, float* __restrict__ C,
        const int* __restrict__ Mptr, int nT,
        double* __restrict__ csum, double* __restrict__ cssum)
{
    const int M = Mptr[0];
    const int nwg = gridDim.x, orig = blockIdx.x;
    const int qq = nwg >> 3, rr = nwg & 7;
    const int xcd = orig & 7, idx = orig >> 3;
    const int lin = (xcd < rr ? xcd * (qq + 1) : rr * (qq + 1) + (xcd - rr) * qq) + idx;
    const int bmI = lin / nT;
    const int bm = bmI * 128, bn = (lin - bmI * nT) * 128;
    if (bm >= M) return;
    __shared__ __align__(16) _Float16 smem[2][2][128 * 32];
    const int tid = threadIdx.x, lane = tid & 63, wave = tid >> 6;
    const int rIn = lane >> 2;
    const int kSrcByte = ((((lane & 3) - ((lane >> 3) & 3)) & 3) << 4);
    const int wr = wave >> 1, wc = wave & 1;
    const int lr = lane & 15, kb = lane >> 4;
    const int pGr = ((kb + ((lr >> 1) & 3)) & 3) << 3;
    f4 acc[4][4] = {};

    auto STAGE = [&](int b, int k0) {
        const bool isA = (wave < 2);
        const _Float16* gp = isA ? Ag : Bh;
        _Float16* lp = smem[b][isA ? 0 : 1];
        const int tb = isA ? bm : bn;
        const int hf = wave & 1;
#pragma unroll
        for (int c2 = 0; c2 < 4; ++c2) {
            int c = hf * 4 + c2;
            int row = tb + c * 16 + rIn;
            if (isA) row = min(row, M - 1);
            gl_lds16((const char*)gp + ((size_t)row * H1 + k0) * 2 + kSrcByte, lp + c * 512);
        }
    };

    int cur = 0;
    STAGE(0, 0);
    for (int k0 = 0; k0 < H1; k0 += 32) {
        __syncthreads();
        if (k0 + 32 < H1) STAGE(cur ^ 1, k0 + 32);
        const _Float16* AhP = smem[cur][0];
        const _Float16* BhP = smem[cur][1];
        const int ar = (wr * 64 + lr) * 32 + pGr;
        const int br = (wc * 64 + lr) * 32 + pGr;
        h8 ahf[4], bhf[4];
#pragma unroll
        for (int i = 0; i < 4; ++i) {
            ahf[i] = *(const h8*)&AhP[ar + i * 512];
            bhf[i] = *(const h8*)&BhP[br + i * 512];
        }
#pragma unroll
        for (int mi = 0; mi < 4; ++mi)
#pragma unroll
            for (int ni = 0; ni < 4; ++ni)
                acc[mi][ni] = __builtin_amdgcn_mfma_f32_16x16x32_f16(ahf[mi], bhf[ni], acc[mi][ni], 0, 0, 0);
        cur ^= 1;
    }
#pragma unroll
    for (int ni = 0; ni < 4; ++ni) {
        const int col = bn + wc * 64 + ni * 16 + lr;
        const float bv = bias[col];
        double sd_ = 0.0, ssd = 0.0;
#pragma unroll
        for (int mi = 0; mi < 4; ++mi)
#pragma unroll
            for (int r = 0; r < 4; ++r) {
                int row = bm + wr * 64 + mi * 16 + kb * 4 + r;
                if (row < M) {
                    float v = acc[mi][ni][r] + bv;
                    C[(size_t)row * H2 + col] = v;
                    sd_ += (double)v;
                    ssd += (double)v * (double)v;
                }
            }
        sd_ += __shfl_xor(sd_, 16); ssd += __shfl_xor(ssd, 16);
        sd_ += __shfl_xor(sd_, 32); ssd += __shfl_xor(ssd, 32);
        if (kb == 0) {
            atomicAdd(&csum[col], sd_);
            atomicAdd(&cssum[col], ssd);
        }
    }
}

// ---------- BN params ----------
__global__ void bnparam_kernel(const double* __restrict__ s, const double* __restrict__ ss,
                               const float* __restrict__ g, const float* __restrict__ be,
                               float* __restrict__ a, float* __restrict__ bb, int cols,
                               const float* __restrict__ padBias, const int* __restrict__ CvPtr) {
    int j = blockIdx.x * blockDim.x + threadIdx.x;
    if (j >= cols) return;
    double sum = s[j], sumsq = ss[j];
    if (CvPtr) {
        double pad = (double)(Nn - CvPtr[0]);
        double bv = padBias ? (double)padBias[j] : 0.0;
        sum += pad * bv; sumsq += pad * bv * bv;
    }
    double mean = sum / (double)Nn;
    double var = sumsq / (double)Nn - mean * mean;
    float aj = g[j] / sqrtf((float)var + EPSc);
    a[j] = aj;
    bb[j] = be[j] - (float)mean * aj;
}

// ---------- p,q row dots over BN+ReLU(h), no write-back; one WAVE per node ----------
__global__ __launch_bounds__(256) void pq_kernel(const float* __restrict__ h,
        const float* __restrict__ a, const float* __restrict__ bb,
        const float* __restrict__ Wp, float* __restrict__ p, float* __restrict__ q) {
    const int n = blockIdx.x * 4 + (threadIdx.x >> 6);
    if (n >= Nn) return;
    const int lane = threadIdx.x & 63;
    float sp = 0.f, sq = 0.f;
    const float* row = h + (size_t)n * H1;
#pragma unroll
    for (int u = 0; u < 4; ++u) {
        int j = u * 256 + lane * 4;
        float4 v = *(const float4*)(row + j);
        const float4 av = *(const float4*)(a + j);
        const float4 bv = *(const float4*)(bb + j);
        v.x = fmaxf(v.x * av.x + bv.x, 0.f);
        v.y = fmaxf(v.y * av.y + bv.y, 0.f);
        v.z = fmaxf(v.z * av.z + bv.z, 0.f);
        v.w = fmaxf(v.w * av.w + bv.w, 0.f);
        const float4 wp = *(const float4*)(Wp + j);
        const float4 wq = *(const float4*)(Wp + H1 + j);
        sp += v.x * wp.x + v.y * wp.y + v.z * wp.z + v.w * wp.w;
        sq += v.x * wq.x + v.y * wq.y + v.z * wq.z + v.w * wq.w;
    }
#pragma unroll
    for (int off = 32; off > 0; off >>= 1) {
        sp += __shfl_xor(sp, off);
        sq += __shfl_xor(sq, off);
    }
    if (lane == 0) { p[n] = sp; q[n] = sq; }
}

// ---------- fused edge-score + greedy matching, one block per graph ----------
__global__ __launch_bounds__(1024) void match_fused_kernel(
        const int* __restrict__ ei,
        const float* __restrict__ p, const float* __restrict__ q,
        const float* __restrict__ bp,
        unsigned long long* __restrict__ packed,
        int* __restrict__ nodeA, int* __restrict__ nodeB,
        float* __restrict__ multc, int* __restrict__ scal,
        int* __restrict__ gbase, int* __restrict__ gcnt) {
    __shared__ __align__(16) char LB[52096];
    unsigned short* lst = (unsigned short*)LB;            // [2][8000]
    float* earr = (float*)LB;
    float* pl = (float*)(LB + 32000);
    float* ql = pl + NPg;
    unsigned long long* best = (unsigned long long*)(LB + 32000);
    unsigned* maxu = (unsigned*)(LB + 40000);
    int* mergedS = (int*)(LB + 40000);
    unsigned long long* den = (unsigned long long*)(LB + 44000);
    float* lmult = (float*)(LB + 44000);
    unsigned short* lsA = (unsigned short*)(LB + 48000);
    unsigned short* ldA = (unsigned short*)(LB + 50000);
    int* cnts = (int*)(LB + 52032);

    const int g = blockIdx.x;
    const int tid = threadIdx.x;
    const int e0 = g * EPg, n0 = g * NPg;
    const int* srcp = ei + e0;
    const int* dstp = ei + Ee + e0;
    const float bpv = bp[0];

    for (int i = tid; i < NPg; i += 1024) {
        pl[i] = p[n0 + i];
        ql[i] = q[n0 + i];
        maxu[i] = 0u;
        den[i] = 0ull;
    }
    __syncthreads();
    for (int i = tid; i < EPg; i += 1024) {
        int s = srcp[i] - n0, d = dstp[i] - n0;
        float e = pl[s] + ql[d] + bpv;
        earr[i] = e;
        atomicMax(&maxu[d], fmap(e));
    }
    __syncthreads();
    for (int i = tid; i < EPg; i += 1024) {
        int d = dstp[i] - n0;
        float ex = expf(earr[i] - funmap(maxu[d]));
        atomicAdd(&den[d], (unsigned long long)(ex * 4294967296.0f));
    }
    __syncthreads();
    for (int i = tid; i < EPg; i += 1024) {
        int s = srcp[i] - n0, d = dstp[i] - n0;
        float ex = expf(earr[i] - funmap(maxu[d]));
        float den_f = (float)((double)den[d] * (1.0 / 4294967296.0));
        float sc = ex / den_f + 0.5f;
        packed[e0 + i] = ((unsigned long long)__float_as_uint(sc) << 33)
                       | ((unsigned long long)(8191u - (unsigned)i) << 20)
                       | ((unsigned long long)(unsigned)s << 10) | (unsigned long long)(unsigned)d;
    }
    __syncthreads();
    for (int i = tid; i < NPg; i += 1024) mergedS[i] = 0;
    for (int i = tid; i < EPg; i += 1024) lst[i] = (unsigned short)i;
    if (tid == 0) { cnts[0] = EPg; cnts[1] = 0; cnts[2] = 0; }
    __syncthreads();
    int cur = 0;
    for (int round = 0; round < 20000; ++round) {
        const int n_cur = cnts[cur];
        if (n_cur == 0) break;
        if (tid == 0) cnts[cur ^ 1] = 0;
        for (int i = tid; i < NPg; i += 1024) best[i] = 0ull;
        __syncthreads();
        for (int ii = tid; ii < n_cur; ii += 1024) {
            int le = lst[cur * EPg + ii];
            unsigned long long pk = packed[e0 + le];
            int s = (int)((pk >> 10) & 1023), d = (int)(pk & 1023);
            if (mergedS[s] | mergedS[d]) { lst[cur * EPg + ii] = 0xFFFF; continue; }
            atomicMax(&best[s], pk);
            atomicMax(&best[d], pk);
        }
        __syncthreads();
        for (int ii = tid; ii < n_cur; ii += 1024) {
            int le = lst[cur * EPg + ii];
            if (le == 0xFFFF) continue;
            unsigned long long pk = packed[e0 + le];
            int s = (int)((pk >> 10) & 1023), d = (int)(pk & 1023);
            if (best[s] == pk && best[d] == pk) {
                int c = atomicAdd(&cnts[2], 1);
                lsA[c] = (unsigned short)s;
                ldA[c] = (s == d) ? (unsigned short)0xFFFF : (unsigned short)d;
                lmult[c] = __uint_as_float((unsigned)(pk >> 33));
                mergedS[s] = 1;
                if (d != s) mergedS[d] = 1;
            } else {
                int pos = atomicAdd(&cnts[cur ^ 1], 1);
                lst[(cur ^ 1) * EPg + pos] = (unsigned short)le;
            }
        }
        __syncthreads();
        cur ^= 1;
    }
    for (int i = tid; i < NPg; i += 1024) {
        if (!mergedS[i]) {
            int c = atomicAdd(&cnts[2], 1);
            lsA[c] = (unsigned short)i;
            ldA[c] = 0xFFFF;
            lmult[c] = 1.0f;
        }
    }
    __syncthreads();
    if (tid == 0) {
        int ncl = cnts[2];
        int base = atomicAdd(&scal[2], ncl);
        cnts[3] = base;
        gbase[g] = base;
        gcnt[g] = ncl;
    }
    __syncthreads();
    const int ncl = cnts[2], base = cnts[3];
    for (int i = tid; i < ncl; i += 1024) {
        nodeA[base + i] = n0 + (int)lsA[i];
        nodeB[base + i] = (ldA[i] == 0xFFFF) ? -1 : (n0 + (int)ldA[i]);
        multc[base + i] = lmult[i];
    }
}

// ---------- gather clustered rows: Ag[c] = f16(mult*(relu(bn(h[a]))+relu(bn(h[b])))) ----------
__global__ __launch_bounds__(256) void gather_kernel(const float* __restrict__ h,
        const float* __restrict__ a, const float* __restrict__ bb,
        const int* __restrict__ nodeA, const int* __restrict__ nodeB,
        const float* __restrict__ multc, const int* __restrict__ scal,
        _Float16* __restrict__ Ag) {
    int c = blockIdx.x * 4 + (threadIdx.x >> 6);
    if (c >= scal[2]) return;
    const int lane = threadIdx.x & 63;
    int na = nodeA[c], nb = nodeB[c];
    float mu = multc[c];
#pragma unroll
    for (int u = 0; u < 4; ++u) {
        int j = u * 256 + lane * 4;
        const float4 av = *(const float4*)(a + j);
        const float4 bv = *(const float4*)(bb + j);
        float4 v = *(const float4*)(h + (size_t)na * H1 + j);
        v.x = fmaxf(v.x * av.x + bv.x, 0.f);
        v.y = fmaxf(v.y * av.y + bv.y, 0.f);
        v.z = fmaxf(v.z * av.z + bv.z, 0.f);
        v.w = fmaxf(v.w * av.w + bv.w, 0.f);
        if (nb >= 0) {
            float4 w = *(const float4*)(h + (size_t)nb * H1 + j);
            v.x += fmaxf(w.x * av.x + bv.x, 0.f);
            v.y += fmaxf(w.y * av.y + bv.y, 0.f);
            v.z += fmaxf(w.z * av.z + bv.z, 0.f);
            v.w += fmaxf(w.w * av.w + bv.w, 0.f);
        }
        h4 o = { (_Float16)(mu * v.x), (_Float16)(mu * v.y), (_Float16)(mu * v.z), (_Float16)(mu * v.w) };
        *(h4*)(Ag + (size_t)c * H1 + j) = o;
    }
}

// ---------- BN2+ReLU+per-graph sum pool over contiguous segments (no atomics) ----------
__global__ __launch_bounds__(256) void pool_seg_kernel(const float* __restrict__ C2,
        const float* __restrict__ a2, const float* __restrict__ bb2,
        const int* __restrict__ gbase, const int* __restrict__ gcnt,
        float* __restrict__ pool) {
    const int g = blockIdx.x;
    const int j = blockIdx.y * 256 + threadIdx.x;
    const int b0 = gbase[g], cN = gcnt[g];
    const float aj = a2[j], bj = bb2[j];
    float s = 0.f;
    for (int c = b0; c < b0 + cN; ++c)
        s += fmaxf(C2[(size_t)c * H2 + j] * aj + bj, 0.f);
    pool[g * H2 + j] = s;
}

// ---------- FC layers ----------
__global__ void fc1_kernel(const float* __restrict__ pool, const int* __restrict__ gcnt,
                           const float* __restrict__ Wfc, const float* __restrict__ bfc,
                           float* __restrict__ hid) {
    int g = blockIdx.x;
    int o = threadIdx.x;
    float inv = 1.0f / fmaxf((float)gcnt[g], 1.0f);
    if (o < 200) {
        float s = 0.f;
        for (int j = 0; j < H2; ++j) s += (pool[g * H2 + j] * inv) * Wfc[o * H2 + j];
        hid[g * 200 + o] = fmaxf(s + bfc[o], 0.f);
    }
}
__global__ void fc2_kernel(const float* __restrict__ hid, const float* __restrict__ Wfc1,
                           const float* __restrict__ bfc1, float* __restrict__ out) {
    int idx = threadIdx.x;
    if (idx < Bb * OUTd) {
        int g = idx / OUTd, o = idx % OUTd;
        float s = bfc1[o];
        for (int t = 0; t < 200; ++t) s += hid[g * 200 + t] * Wfc1[o * 200 + t];
        out[idx] = s;
    }
}

extern "C" void kernel_launch(void* const* d_in, const int* in_sizes, int n_in,
                              void* d_out, int out_size, void* d_ws, size_t ws_size,
                              hipStream_t stream) {
    (void)in_sizes; (void)n_in; (void)out_size; (void)ws_size;
    const float* x    = (const float*)d_in[0];
    const int*   ei   = (const int*)d_in[1];
    const float* W1   = (const float*)d_in[3];
    const float* b1   = (const float*)d_in[4];
    const float* g1   = (const float*)d_in[5];
    const float* be1  = (const float*)d_in[6];
    const float* Wp   = (const float*)d_in[7];
    const float* bp   = (const float*)d_in[8];
    const float* W2   = (const float*)d_in[9];
    const float* b2   = (const float*)d_in[10];
    const float* g2   = (const float*)d_in[11];
    const float* be2  = (const float*)d_in[12];
    const float* Wfc  = (const float*)d_in[13];
    const float* bfc  = (const float*)d_in[14];
    const float* Wfc1 = (const float*)d_in[15];
    const float* bfc1 = (const float*)d_in[16];

    char* w = (char*)d_ws;
    auto take = [&](size_t bytes) -> char* {
        char* r = w;
        w += (bytes + 255) & ~(size_t)255;
        return r;
    };
    // R1: h (f32) -> reused as gemm2 output C2 after gather
    float* h      = (float*)take((size_t)Nn * H1 * 4);          // 204.8 MB
    // R2: xhi|xlo -> reused as Ag (f16 gathered rows) after matching
    _Float16* xhi = (_Float16*)take((size_t)Nn * Ff * 2);       // 51.2 MB
    _Float16* xlo = (_Float16*)take((size_t)Nn * Ff * 2);       // 51.2 MB
    _Float16* w1h = (_Float16*)take((size_t)H1 * Ff * 2);
    _Float16* w1l = (_Float16*)take((size_t)H1 * Ff * 2);
    _Float16* w2h = (_Float16*)take((size_t)H2 * H1 * 2);
    float* p      = (float*)take((size_t)Nn * 4);
    float* q      = (float*)take((size_t)Nn * 4);
    unsigned long long* packed = (unsigned long long*)take((size_t)Ee * 8);
    int* nodeA    = (int*)take((size_t)Nn * 4);
    int* nodeB    = (int*)take((size_t)Nn * 4);
    float* multc  = (float*)take((size_t)Nn * 4);
    double* cs1   = (double*)take((size_t)H1 * 8);
    double* css1  = (double*)take((size_t)H1 * 8);
    double* cs2   = (double*)take((size_t)H2 * 8);
    double* css2  = (double*)take((size_t)H2 * 8);
    float* a1     = (float*)take((size_t)H1 * 4);
    float* bb1    = (float*)take((size_t)H1 * 4);
    float* a2     = (float*)take((size_t)H2 * 4);
    float* bb2    = (float*)take((size_t)H2 * 4);
    float* pool   = (float*)take((size_t)Bb * H2 * 4);
    float* hid    = (float*)take((size_t)Bb * 200 * 4);
    int* scal     = (int*)take(64 * 4);
    int* gbase    = (int*)take(64 * 4);
    int* gcnt     = (int*)take(64 * 4);
    _Float16* Ag  = xhi;   // alias after gemm1
    float* C2o    = h;     // alias after gather

    const int mT  = (Nn + 127) / 128;   // 391 (gemm2)
    const int mT2 = (Nn + 255) / 256;   // 196 (gemm1 256^2)

    prep_kernel<<<dim3(2048), dim3(256), 0, stream>>>(x, xhi, xlo, W1, w1h, w1l, W2, w2h,
                                                      cs1, css1, cs2, css2, scal);
    gemm1_256_kernel<<<dim3(mT2 * (H1 / 256)), dim3(512), 0, stream>>>(
        xhi, xlo, w1h, w1l, b1, h, cs1, css1);
    bnparam_kernel<<<dim3((H1 + 255) / 256), dim3(256), 0, stream>>>(cs1, css1, g1, be1, a1, bb1, H1, (const float*)nullptr, (const int*)nullptr);
    pq_kernel<<<dim3((Nn + 3) / 4), dim3(256), 0, stream>>>(h, a1, bb1, Wp, p, q);
    match_fused_kernel<<<dim3(Bb), dim3(1024), 0, stream>>>(ei, p, q, bp, packed,
        nodeA, nodeB, multc, scal, gbase, gcnt);
    gather_kernel<<<dim3((Nn + 3) / 4), dim3(256), 0, stream>>>(h, a1, bb1, nodeA, nodeB, multc, scal, Ag);
    gemm2_kernel<<<dim3(mT * (H2 / 128)), dim3(256), 0, stream>>>(
        Ag, w2h, b2, C2o, scal + 2, H2 / 128, cs2, css2);
    bnparam_kernel<<<dim3((H2 + 255) / 256), dim3(256), 0, stream>>>(cs2, css2, g2, be2, a2, bb2, H2, b2, scal + 2);
    pool_seg_kernel<<<dim3(Bb, H2 / 256), dim3(256), 0, stream>>>(C2o, a2, bb2, gbase, gcnt, pool);
    fc1_kernel<<<dim3(Bb), dim3(256), 0, stream>>>(pool, gcnt, Wfc, bfc, hid);
    fc2_kernel<<<dim3(1), dim3(512), 0, stream>>>(hid, Wfc1, bfc1, (float*)d_out);
}

// Round 18
// 668.302 us; speedup vs baseline: 1.0499x; 1.0178x over previous
//
#include <hip/hip_runtime.h>

#define Nn   50000
#define Ee   400000
#define Ff   512
#define H1   1024
#define H2   512
#define Bb   50
#define OUTd 10
#define EPSc 1e-5f
#define NPg  1000   // nodes per graph
#define EPg  8000   // edges per graph

typedef _Float16 h8 __attribute__((ext_vector_type(8)));
typedef _Float16 h4 __attribute__((ext_vector_type(4)));
typedef float f4 __attribute__((ext_vector_type(4)));

// ---------- monotone float<->uint mapping for atomicMax on floats ----------
__device__ __forceinline__ unsigned fmap(float f) {
    unsigned u = __float_as_uint(f);
    return (u & 0x80000000u) ? ~u : (u | 0x80000000u);
}
__device__ __forceinline__ float funmap(unsigned m) {
    unsigned u = (m & 0x80000000u) ? (m ^ 0x80000000u) : ~m;
    return __uint_as_float(u);
}

__device__ __forceinline__ void gl_lds16(const void* g, void* l) {
    __builtin_amdgcn_global_load_lds(
        (const __attribute__((address_space(1))) unsigned int*)g,
        (__attribute__((address_space(3))) unsigned int*)l,
        16, 0, 0);
}

// ---------- fused prep: zero accumulators + split x, split W1, convert W2 ----------
__global__ void prep_kernel(const float* __restrict__ x, _Float16* __restrict__ xhi, _Float16* __restrict__ xlo,
                            const float* __restrict__ W1, _Float16* __restrict__ w1h, _Float16* __restrict__ w1l,
                            const float* __restrict__ W2, _Float16* __restrict__ w2h,
                            double* __restrict__ cs1, double* __restrict__ css1,
                            double* __restrict__ cs2, double* __restrict__ css2, int* __restrict__ scal) {
    int i = blockIdx.x * blockDim.x + threadIdx.x;
    int nth = gridDim.x * blockDim.x;
    for (int j = i; j < H1; j += nth) { cs1[j] = 0.0; css1[j] = 0.0; }
    for (int j = i; j < H2; j += nth) { cs2[j] = 0.0; css2[j] = 0.0; }
    if (i < 16) scal[i] = 0;
    const int nx = Nn * Ff / 4, nw1 = H1 * Ff / 4, nw2 = H2 * H1 / 4;
    for (int k = i; k < nx; k += nth) {
        float4 v = ((const float4*)x)[k];
        h4 H = { (_Float16)v.x, (_Float16)v.y, (_Float16)v.z, (_Float16)v.w };
        h4 L = { (_Float16)(v.x - (float)H[0]), (_Float16)(v.y - (float)H[1]),
                 (_Float16)(v.z - (float)H[2]), (_Float16)(v.w - (float)H[3]) };
        ((h4*)xhi)[k] = H;
        ((h4*)xlo)[k] = L;
    }
    for (int k = i; k < nw1; k += nth) {
        float4 v = ((const float4*)W1)[k];
        h4 H = { (_Float16)v.x, (_Float16)v.y, (_Float16)v.z, (_Float16)v.w };
        h4 L = { (_Float16)(v.x - (float)H[0]), (_Float16)(v.y - (float)H[1]),
                 (_Float16)(v.z - (float)H[2]), (_Float16)(v.w - (float)H[3]) };
        ((h4*)w1h)[k] = H;
        ((h4*)w1l)[k] = L;
    }
    for (int k = i; k < nw2; k += nth) {
        float4 v = ((const float4*)W2)[k];
        h4 H = { (_Float16)v.x, (_Float16)v.y, (_Float16)v.z, (_Float16)v.w };
        ((h4*)w2h)[k] = H;
    }
}

// ---------- GEMM1: 256x256 SPLIT tile, BK=32, 8 waves (2Mx4N, 128x64 each),
// 128 KB LDS double-buffer (all 4 operand arrays DMA-staged), ONE barrier per
// K-step, XCD-chunk + granule swizzle. C = Ahi*Bhi + Ahi*Blo + Alo*Bhi —
// per-element FP chain identical across tile variants -> bit-identical h.
// (Proven best of the 2-phase family: 232us; counted-vmcnt/1-buf/B-direct all worse.)
__global__ __launch_bounds__(512) void gemm1_256_kernel(
        const _Float16* __restrict__ Ahi, const _Float16* __restrict__ Alo,
        const _Float16* __restrict__ Bhi, const _Float16* __restrict__ Blo,
        const float* __restrict__ bias, float* __restrict__ C,
        double* __restrict__ csum, double* __restrict__ cssum)
{
    const int M = Nn;
    const int nwg = gridDim.x, orig = blockIdx.x;
    const int qq = nwg >> 3, rr = nwg & 7;
    const int xcd = orig & 7, idx = orig >> 3;
    const int lin = (xcd < rr ? xcd * (qq + 1) : rr * (qq + 1) + (xcd - rr) * qq) + idx;
    const int nT = H1 / 256;                   // 4
    const int bmI = lin / nT;
    const int bm = bmI * 256, bn = (lin - bmI * nT) * 256;
    __shared__ __align__(16) _Float16 smem[2][4][256 * 32];   // 128 KB
    const int tid = threadIdx.x, lane = tid & 63, wave = tid >> 6;   // 8 waves
    const int rIn = lane >> 2;
    const int kSrcByte = ((((lane & 3) - ((lane >> 3) & 3)) & 3) << 4);
    const int wr = wave >> 2, wc = wave & 3;   // wave grid 2(M) x 4(N)
    const int lr = lane & 15, kb = lane >> 4;
    const int pGr = ((kb + ((lr >> 1) & 3)) & 3) << 3;
    const int arr = wave >> 1;                 // 0=Ah 1=Al 2=Bh 3=Bl
    const int hv = wave & 1;                   // row half of the array
    const bool isA = (arr < 2);
    const _Float16* gp = (arr == 0) ? Ahi : (arr == 1) ? Alo : (arr == 2) ? Bhi : Blo;
    const int tb = isA ? bm : bn;
    f4 acc[8][4] = {};

    auto STAGE = [&](int b, int k0) {
        _Float16* lp = smem[b][arr] + hv * (128 * 32);
#pragma unroll
        for (int c = 0; c < 8; ++c) {
            int row = tb + hv * 128 + c * 16 + rIn;
            if (isA) row = min(row, M - 1);
            gl_lds16((const char*)gp + ((size_t)row * Ff + k0) * 2 + kSrcByte, lp + c * 512);
        }
    };

    int cur = 0;
    STAGE(0, 0);
    for (int k0 = 0; k0 < Ff; k0 += 32) {
        __syncthreads();
        if (k0 + 32 < Ff) STAGE(cur ^ 1, k0 + 32);
        const _Float16* AhP = smem[cur][0];
        const _Float16* AlP = smem[cur][1];
        const _Float16* BhP = smem[cur][2];
        const _Float16* BlP = smem[cur][3];
        h8 ahf[8], alf[8];
#pragma unroll
        for (int mi = 0; mi < 8; ++mi) {
            const int ar = (wr * 128 + mi * 16 + lr) * 32 + pGr;
            ahf[mi] = *(const h8*)&AhP[ar];
            alf[mi] = *(const h8*)&AlP[ar];
        }
#pragma unroll
        for (int ni = 0; ni < 4; ++ni) {
            const int br = (wc * 64 + ni * 16 + lr) * 32 + pGr;
            const h8 bh = *(const h8*)&BhP[br];
            const h8 bl = *(const h8*)&BlP[br];
#pragma unroll
            for (int mi = 0; mi < 8; ++mi) {
                acc[mi][ni] = __builtin_amdgcn_mfma_f32_16x16x32_f16(ahf[mi], bh, acc[mi][ni], 0, 0, 0);
                acc[mi][ni] = __builtin_amdgcn_mfma_f32_16x16x32_f16(ahf[mi], bl, acc[mi][ni], 0, 0, 0);
                acc[mi][ni] = __builtin_amdgcn_mfma_f32_16x16x32_f16(alf[mi], bh, acc[mi][ni], 0, 0, 0);
            }
        }
        cur ^= 1;
    }
    // epilogue: bias, store, fused column stats. C/D map: col=lane&15, row=(lane>>4)*4+reg
#pragma unroll
    for (int ni = 0; ni < 4; ++ni) {
        const int col = bn + wc * 64 + ni * 16 + lr;
        const float bv = bias[col];
        double sd_ = 0.0, ssd = 0.0;
#pragma unroll
        for (int mi = 0; mi < 8; ++mi)
#pragma unroll
            for (int r = 0; r < 4; ++r) {
                int row = bm + wr * 128 + mi * 16 + kb * 4 + r;
                if (row < M) {
                    float v = acc[mi][ni][r] + bv;
                    C[(size_t)row * H1 + col] = v;
                    sd_ += (double)v;
                    ssd += (double)v * (double)v;
                }
            }
        sd_ += __shfl_xor(sd_, 16); ssd += __shfl_xor(ssd, 16);
        sd_ += __shfl_xor(sd_, 32); ssd += __shfl_xor(ssd, 32);
        if (kb == 0) {
            atomicAdd(&csum[col], sd_);
            atomicAdd(&cssum[col], ssd);
        }
    }
}

// ---------- GEMM2: 128x128 non-split (round-7 proven schedule, dbuf LDS staging) ----------
__global__ __launch_bounds__(256) void gemm2_kernel(
        const _Float16* __restrict__ Ag, const _Float16* __restrict__ Bh,
        const float* __restrict__ bias, float* __restrict__ C,
        const int* __restrict__ Mptr, int nT,
        double* __restrict__ csum, double* __restrict__ cssum)
{
    const int M = Mptr[0];
    const int nwg = gridDim.x, orig = blockIdx.x;
    const int qq = nwg >> 3, rr = nwg & 7;
    const int xcd = orig & 7, idx = orig >> 3;
    const int lin = (xcd < rr ? xcd * (qq + 1) : rr * (qq + 1) + (xcd - rr) * qq) + idx;
    const int bmI = lin / nT;
    const int bm = bmI * 128, bn = (lin - bmI * nT) * 128;
    if (bm >= M) return;
    __shared__ __align__(16) _Float16 smem[2][2][128 * 32];
    const int tid = threadIdx.x, lane = tid & 63, wave = tid >> 6;
    const int rIn = lane >> 2;
    const int kSrcByte = ((((lane & 3) - ((lane >> 3) & 3)) & 3) << 4);
    const int wr = wave >> 1, wc = wave & 1;
    const int lr = lane & 15, kb = lane >> 4;
    const int pGr = ((kb + ((lr >> 1) & 3)) & 3) << 3;
    f4 acc[4][4] = {};

    auto STAGE = [&](int b, int k0) {
        const bool isA = (wave < 2);
        const _Float16* gp = isA ? Ag : Bh;
        _Float16* lp = smem[b][isA ? 0 : 1];
        const int tb = isA ? bm : bn;
        const int hf = wave & 1;
#pragma unroll
        for (int c2 = 0; c2 < 4; ++c2) {
            int c = hf * 4 + c2;
            int row = tb + c * 16 + rIn;
            if (isA) row = min(row, M - 1);
            gl_lds16((const char*)gp + ((size_t)row * H1 + k0) * 2 + kSrcByte, lp + c * 512);
        }
    };

    int cur = 0;
    STAGE(0, 0);
    for (int k0 = 0; k0 < H1; k0 += 32) {
        __syncthreads();
        if (k0 + 32 < H1) STAGE(cur ^ 1, k0 + 32);
        const _Float16* AhP = smem[cur][0];
        const _Float16* BhP = smem[cur][1];
        const int ar = (wr * 64 + lr) * 32 + pGr;
        const int br = (wc * 64 + lr) * 32 + pGr;
        h8 ahf[4], bhf[4];
#pragma unroll
        for (int i = 0; i < 4; ++i) {
            ahf[i] = *(const h8*)&AhP[ar + i * 512];
            bhf[i] = *(const h8*)&BhP[br + i * 512];
        }
#pragma unroll
        for (int mi = 0; mi < 4; ++mi)
#pragma unroll
            for (int ni = 0; ni < 4; ++ni)
                acc[mi][ni] = __builtin_amdgcn_mfma_f32_16x16x32_f16(ahf[mi], bhf[ni], acc[mi][ni], 0, 0, 0);
        cur ^= 1;
    }
#pragma unroll
    for (int ni = 0; ni < 4; ++ni) {
        const int col = bn + wc * 64 + ni * 16 + lr;
        const float bv = bias[col];
        double sd_ = 0.0, ssd = 0.0;
#pragma unroll
        for (int mi = 0; mi < 4; ++mi)
#pragma unroll
            for (int r = 0; r < 4; ++r) {
                int row = bm + wr * 64 + mi * 16 + kb * 4 + r;
                if (row < M) {
                    float v = acc[mi][ni][r] + bv;
                    C[(size_t)row * H2 + col] = v;
                    sd_ += (double)v;
                    ssd += (double)v * (double)v;
                }
            }
        sd_ += __shfl_xor(sd_, 16); ssd += __shfl_xor(ssd, 16);
        sd_ += __shfl_xor(sd_, 32); ssd += __shfl_xor(ssd, 32);
        if (kb == 0) {
            atomicAdd(&csum[col], sd_);
            atomicAdd(&cssum[col], ssd);
        }
    }
}

// ---------- BN1 params ----------
__global__ void bnparam_kernel(const double* __restrict__ s, const double* __restrict__ ss,
                               const float* __restrict__ g, const float* __restrict__ be,
                               float* __restrict__ a, float* __restrict__ bb, int cols) {
    int j = blockIdx.x * blockDim.x + threadIdx.x;
    if (j >= cols) return;
    double sum = s[j], sumsq = ss[j];
    double mean = sum / (double)Nn;
    double var = sumsq / (double)Nn - mean * mean;
    float aj = g[j] / sqrtf((float)var + EPSc);
    a[j] = aj;
    bb[j] = be[j] - (float)mean * aj;
}

// ---------- p,q row dots over BN+ReLU(h), no write-back; one WAVE per node ----------
__global__ __launch_bounds__(256) void pq_kernel(const float* __restrict__ h,
        const float* __restrict__ a, const float* __restrict__ bb,
        const float* __restrict__ Wp, float* __restrict__ p, float* __restrict__ q) {
    const int n = blockIdx.x * 4 + (threadIdx.x >> 6);
    if (n >= Nn) return;
    const int lane = threadIdx.x & 63;
    float sp = 0.f, sq = 0.f;
    const float* row = h + (size_t)n * H1;
#pragma unroll
    for (int u = 0; u < 4; ++u) {
        int j = u * 256 + lane * 4;
        float4 v = *(const float4*)(row + j);
        const float4 av = *(const float4*)(a + j);
        const float4 bv = *(const float4*)(bb + j);
        v.x = fmaxf(v.x * av.x + bv.x, 0.f);
        v.y = fmaxf(v.y * av.y + bv.y, 0.f);
        v.z = fmaxf(v.z * av.z + bv.z, 0.f);
        v.w = fmaxf(v.w * av.w + bv.w, 0.f);
        const float4 wp = *(const float4*)(Wp + j);
        const float4 wq = *(const float4*)(Wp + H1 + j);
        sp += v.x * wp.x + v.y * wp.y + v.z * wp.z + v.w * wp.w;
        sq += v.x * wq.x + v.y * wq.y + v.z * wq.z + v.w * wq.w;
    }
#pragma unroll
    for (int off = 32; off > 0; off >>= 1) {
        sp += __shfl_xor(sp, off);
        sq += __shfl_xor(sq, off);
    }
    if (lane == 0) { p[n] = sp; q[n] = sq; }
}

// ---------- fused edge-score + greedy matching, one block per graph ----------
__global__ __launch_bounds__(1024) void match_fused_kernel(
        const int* __restrict__ ei,
        const float* __restrict__ p, const float* __restrict__ q,
        const float* __restrict__ bp,
        unsigned long long* __restrict__ packed,
        int* __restrict__ nodeA, int* __restrict__ nodeB,
        float* __restrict__ multc, int* __restrict__ scal,
        int* __restrict__ gbase, int* __restrict__ gcnt) {
    __shared__ __align__(16) char LB[52096];
    unsigned short* lst = (unsigned short*)LB;            // [2][8000]
    float* earr = (float*)LB;
    float* pl = (float*)(LB + 32000);
    float* ql = pl + NPg;
    unsigned long long* best = (unsigned long long*)(LB + 32000);
    unsigned* maxu = (unsigned*)(LB + 40000);
    int* mergedS = (int*)(LB + 40000);
    unsigned long long* den = (unsigned long long*)(LB + 44000);
    float* lmult = (float*)(LB + 44000);
    unsigned short* lsA = (unsigned short*)(LB + 48000);
    unsigned short* ldA = (unsigned short*)(LB + 50000);
    int* cnts = (int*)(LB + 52032);

    const int g = blockIdx.x;
    const int tid = threadIdx.x;
    const int e0 = g * EPg, n0 = g * NPg;
    const int* srcp = ei + e0;
    const int* dstp = ei + Ee + e0;
    const float bpv = bp[0];

    for (int i = tid; i < NPg; i += 1024) {
        pl[i] = p[n0 + i];
        ql[i] = q[n0 + i];
        maxu[i] = 0u;
        den[i] = 0ull;
    }
    __syncthreads();
    for (int i = tid; i < EPg; i += 1024) {
        int s = srcp[i] - n0, d = dstp[i] - n0;
        float e = pl[s] + ql[d] + bpv;
        earr[i] = e;
        atomicMax(&maxu[d], fmap(e));
    }
    __syncthreads();
    for (int i = tid; i < EPg; i += 1024) {
        int d = dstp[i] - n0;
        float ex = expf(earr[i] - funmap(maxu[d]));
        atomicAdd(&den[d], (unsigned long long)(ex * 4294967296.0f));
    }
    __syncthreads();
    for (int i = tid; i < EPg; i += 1024) {
        int s = srcp[i] - n0, d = dstp[i] - n0;
        float ex = expf(earr[i] - funmap(maxu[d]));
        float den_f = (float)((double)den[d] * (1.0 / 4294967296.0));
        float sc = ex / den_f + 0.5f;
        packed[e0 + i] = ((unsigned long long)__float_as_uint(sc) << 33)
                       | ((unsigned long long)(8191u - (unsigned)i) << 20)
                       | ((unsigned long long)(unsigned)s << 10) | (unsigned long long)(unsigned)d;
    }
    __syncthreads();
    for (int i = tid; i < NPg; i += 1024) mergedS[i] = 0;
    for (int i = tid; i < EPg; i += 1024) lst[i] = (unsigned short)i;
    if (tid == 0) { cnts[0] = EPg; cnts[1] = 0; cnts[2] = 0; }
    __syncthreads();
    int cur = 0;
    for (int round = 0; round < 20000; ++round) {
        const int n_cur = cnts[cur];
        if (n_cur == 0) break;
        if (tid == 0) cnts[cur ^ 1] = 0;
        for (int i = tid; i < NPg; i += 1024) best[i] = 0ull;
        __syncthreads();
        for (int ii = tid; ii < n_cur; ii += 1024) {
            int le = lst[cur * EPg + ii];
            unsigned long long pk = packed[e0 + le];
            int s = (int)((pk >> 10) & 1023), d = (int)(pk & 1023);
            if (mergedS[s] | mergedS[d]) { lst[cur * EPg + ii] = 0xFFFF; continue; }
            atomicMax(&best[s], pk);
            atomicMax(&best[d], pk);
        }
        __syncthreads();
        for (int ii = tid; ii < n_cur; ii += 1024) {
            int le = lst[cur * EPg + ii];
            if (le == 0xFFFF) continue;
            unsigned long long pk = packed[e0 + le];
            int s = (int)((pk >> 10) & 1023), d = (int)(pk & 1023);
            if (best[s] == pk && best[d] == pk) {
                int c = atomicAdd(&cnts[2], 1);
                lsA[c] = (unsigned short)s;
                ldA[c] = (s == d) ? (unsigned short)0xFFFF : (unsigned short)d;
                lmult[c] = __uint_as_float((unsigned)(pk >> 33));
                mergedS[s] = 1;
                if (d != s) mergedS[d] = 1;
            } else {
                int pos = atomicAdd(&cnts[cur ^ 1], 1);
                lst[(cur ^ 1) * EPg + pos] = (unsigned short)le;
            }
        }
        __syncthreads();
        cur ^= 1;
    }
    for (int i = tid; i < NPg; i += 1024) {
        if (!mergedS[i]) {
            int c = atomicAdd(&cnts[2], 1);
            lsA[c] = (unsigned short)i;
            ldA[c] = 0xFFFF;
            lmult[c] = 1.0f;
        }
    }
    __syncthreads();
    if (tid == 0) {
        int ncl = cnts[2];
        int base = atomicAdd(&scal[2], ncl);
        cnts[3] = base;
        gbase[g] = base;
        gcnt[g] = ncl;
    }
    __syncthreads();
    const int ncl = cnts[2], base = cnts[3];
    for (int i = tid; i < ncl; i += 1024) {
        nodeA[base + i] = n0 + (int)lsA[i];
        nodeB[base + i] = (ldA[i] == 0xFFFF) ? -1 : (n0 + (int)ldA[i]);
        multc[base + i] = lmult[i];
    }
}

// ---------- gather clustered rows: Ag[c] = f16(mult*(relu(bn(h[a]))+relu(bn(h[b])))) ----------
__global__ __launch_bounds__(256) void gather_kernel(const float* __restrict__ h,
        const float* __restrict__ a, const float* __restrict__ bb,
        const int* __restrict__ nodeA, const int* __restrict__ nodeB,
        const float* __restrict__ multc, const int* __restrict__ scal,
        _Float16* __restrict__ Ag) {
    int c = blockIdx.x * 4 + (threadIdx.x >> 6);
    if (c >= scal[2]) return;
    const int lane = threadIdx.x & 63;
    int na = nodeA[c], nb = nodeB[c];
    float mu = multc[c];
#pragma unroll
    for (int u = 0; u < 4; ++u) {
        int j = u * 256 + lane * 4;
        const float4 av = *(const float4*)(a + j);
        const float4 bv = *(const float4*)(bb + j);
        float4 v = *(const float4*)(h + (size_t)na * H1 + j);
        v.x = fmaxf(v.x * av.x + bv.x, 0.f);
        v.y = fmaxf(v.y * av.y + bv.y, 0.f);
        v.z = fmaxf(v.z * av.z + bv.z, 0.f);
        v.w = fmaxf(v.w * av.w + bv.w, 0.f);
        if (nb >= 0) {
            float4 w = *(const float4*)(h + (size_t)nb * H1 + j);
            v.x += fmaxf(w.x * av.x + bv.x, 0.f);
            v.y += fmaxf(w.y * av.y + bv.y, 0.f);
            v.z += fmaxf(w.z * av.z + bv.z, 0.f);
            v.w += fmaxf(w.w * av.w + bv.w, 0.f);
        }
        h4 o = { (_Float16)(mu * v.x), (_Float16)(mu * v.y), (_Float16)(mu * v.z), (_Float16)(mu * v.w) };
        *(h4*)(Ag + (size_t)c * H1 + j) = o;
    }
}

// ---------- pool: BN2 params computed inline (identical math to bnparam) + seg sum ----------
__global__ __launch_bounds__(256) void pool_seg_kernel(const float* __restrict__ C2,
        const double* __restrict__ cs2, const double* __restrict__ css2,
        const float* __restrict__ g2, const float* __restrict__ be2, const float* __restrict__ b2,
        const int* __restrict__ CvPtr,
        const int* __restrict__ gbase, const int* __restrict__ gcnt,
        float* __restrict__ pool) {
    const int g = blockIdx.x;
    const int j = blockIdx.y * 256 + threadIdx.x;
    // BN2 param for col j (bit-identical sequence to the old bnparam_kernel w/ pad)
    double sum = cs2[j], sumsq = css2[j];
    double pad = (double)(Nn - CvPtr[0]);
    double bv = (double)b2[j];
    sum += pad * bv; sumsq += pad * bv * bv;
    double mean = sum / (double)Nn;
    double var = sumsq / (double)Nn - mean * mean;
    float aj = g2[j] / sqrtf((float)var + EPSc);
    float bj = be2[j] - (float)mean * aj;
    const int b0 = gbase[g], cN = gcnt[g];
    float s = 0.f;
    for (int c = b0; c < b0 + cN; ++c)
        s += fmaxf(C2[(size_t)c * H2 + j] * aj + bj, 0.f);
    pool[g * H2 + j] = s;
}

// ---------- fused FC1+FC2: block g computes hid[g] in LDS then out[g] ----------
__global__ __launch_bounds__(256) void fc_kernel(const float* __restrict__ pool,
        const int* __restrict__ gcnt,
        const float* __restrict__ Wfc, const float* __restrict__ bfc,
        const float* __restrict__ Wfc1, const float* __restrict__ bfc1,
        float* __restrict__ out) {
    __shared__ float hidS[200];
    const int g = blockIdx.x;
    const int o = threadIdx.x;
    float inv = 1.0f / fmaxf((float)gcnt[g], 1.0f);
    if (o < 200) {
        float s = 0.f;
        for (int j = 0; j < H2; ++j) s += (pool[g * H2 + j] * inv) * Wfc[o * H2 + j];
        hidS[o] = fmaxf(s + bfc[o], 0.f);
    }
    __syncthreads();
    if (o < OUTd) {
        float s = bfc1[o];
        for (int t = 0; t < 200; ++t) s += hidS[t] * Wfc1[o * 200 + t];
        out[g * OUTd + o] = s;
    }
}

extern "C" void kernel_launch(void* const* d_in, const int* in_sizes, int n_in,
                              void* d_out, int out_size, void* d_ws, size_t ws_size,
                              hipStream_t stream) {
    (void)in_sizes; (void)n_in; (void)out_size; (void)ws_size;
    const float* x    = (const float*)d_in[0];
    const int*   ei   = (const int*)d_in[1];
    const float* W1   = (const float*)d_in[3];
    const float* b1   = (const float*)d_in[4];
    const float* g1   = (const float*)d_in[5];
    const float* be1  = (const float*)d_in[6];
    const float* Wp   = (const float*)d_in[7];
    const float* bp   = (const float*)d_in[8];
    const float* W2   = (const float*)d_in[9];
    const float* b2   = (const float*)d_in[10];
    const float* g2   = (const float*)d_in[11];
    const float* be2  = (const float*)d_in[12];
    const float* Wfc  = (const float*)d_in[13];
    const float* bfc  = (const float*)d_in[14];
    const float* Wfc1 = (const float*)d_in[15];
    const float* bfc1 = (const float*)d_in[16];

    char* w = (char*)d_ws;
    auto take = [&](size_t bytes) -> char* {
        char* r = w;
        w += (bytes + 255) & ~(size_t)255;
        return r;
    };
    // R1: h (f32) -> reused as gemm2 output C2 after gather
    float* h      = (float*)take((size_t)Nn * H1 * 4);          // 204.8 MB
    // R2: xhi|xlo -> reused as Ag (f16 gathered rows) after matching
    _Float16* xhi = (_Float16*)take((size_t)Nn * Ff * 2);       // 51.2 MB
    _Float16* xlo = (_Float16*)take((size_t)Nn * Ff * 2);       // 51.2 MB
    _Float16* w1h = (_Float16*)take((size_t)H1 * Ff * 2);
    _Float16* w1l = (_Float16*)take((size_t)H1 * Ff * 2);
    _Float16* w2h = (_Float16*)take((size_t)H2 * H1 * 2);
    float* p      = (float*)take((size_t)Nn * 4);
    float* q      = (float*)take((size_t)Nn * 4);
    unsigned long long* packed = (unsigned long long*)take((size_t)Ee * 8);
    int* nodeA    = (int*)take((size_t)Nn * 4);
    int* nodeB    = (int*)take((size_t)Nn * 4);
    float* multc  = (float*)take((size_t)Nn * 4);
    double* cs1   = (double*)take((size_t)H1 * 8);
    double* css1  = (double*)take((size_t)H1 * 8);
    double* cs2   = (double*)take((size_t)H2 * 8);
    double* css2  = (double*)take((size_t)H2 * 8);
    float* a1     = (float*)take((size_t)H1 * 4);
    float* bb1    = (float*)take((size_t)H1 * 4);
    float* pool   = (float*)take((size_t)Bb * H2 * 4);
    int* scal     = (int*)take(64 * 4);
    int* gbase    = (int*)take(64 * 4);
    int* gcnt     = (int*)take(64 * 4);
    _Float16* Ag  = xhi;   // alias after gemm1
    float* C2o    = h;     // alias after gather

    const int mT  = (Nn + 127) / 128;   // 391 (gemm2)
    const int mT2 = (Nn + 255) / 256;   // 196 (gemm1 256^2)

    prep_kernel<<<dim3(2048), dim3(256), 0, stream>>>(x, xhi, xlo, W1, w1h, w1l, W2, w2h,
                                                      cs1, css1, cs2, css2, scal);
    gemm1_256_kernel<<<dim3(mT2 * (H1 / 256)), dim3(512), 0, stream>>>(
        xhi, xlo, w1h, w1l, b1, h, cs1, css1);
    bnparam_kernel<<<dim3((H1 + 255) / 256), dim3(256), 0, stream>>>(cs1, css1, g1, be1, a1, bb1, H1);
    pq_kernel<<<dim3((Nn + 3) / 4), dim3(256), 0, stream>>>(h, a1, bb1, Wp, p, q);
    match_fused_kernel<<<dim3(Bb), dim3(1024), 0, stream>>>(ei, p, q, bp, packed,
        nodeA, nodeB, multc, scal, gbase, gcnt);
    gather_kernel<<<dim3((Nn + 3) / 4), dim3(256), 0, stream>>>(h, a1, bb1, nodeA, nodeB, multc, scal, Ag);
    gemm2_kernel<<<dim3(mT * (H2 / 128)), dim3(256), 0, stream>>>(
        Ag, w2h, b2, C2o, scal + 2, H2 / 128, cs2, css2);
    pool_seg_kernel<<<dim3(Bb, H2 / 256), dim3(256), 0, stream>>>(
        C2o, cs2, css2, g2, be2, b2, scal + 2, gbase, gcnt, pool);
    fc_kernel<<<dim3(Bb), dim3(256), 0, stream>>>(pool, gcnt, Wfc, bfc, Wfc1, bfc1, (float*)d_out);
}

// Round 19
// 663.003 us; speedup vs baseline: 1.0583x; 1.0080x over previous
//
#include <hip/hip_runtime.h>

#define Nn   50000
#define Ee   400000
#define Ff   512
#define H1   1024
#define H2   512
#define Bb   50
#define OUTd 10
#define EPSc 1e-5f
#define NPg  1000   // nodes per graph
#define EPg  8000   // edges per graph

typedef _Float16 h8 __attribute__((ext_vector_type(8)));
typedef _Float16 h4 __attribute__((ext_vector_type(4)));
typedef float f4 __attribute__((ext_vector_type(4)));

// ---------- monotone float<->uint mapping for atomicMax on floats ----------
__device__ __forceinline__ unsigned fmap(float f) {
    unsigned u = __float_as_uint(f);
    return (u & 0x80000000u) ? ~u : (u | 0x80000000u);
}
__device__ __forceinline__ float funmap(unsigned m) {
    unsigned u = (m & 0x80000000u) ? (m ^ 0x80000000u) : ~m;
    return __uint_as_float(u);
}

__device__ __forceinline__ void gl_lds16(const void* g, void* l) {
    __builtin_amdgcn_global_load_lds(
        (const __attribute__((address_space(1))) unsigned int*)g,
        (__attribute__((address_space(3))) unsigned int*)l,
        16, 0, 0);
}

// ---------- fused prep: zero accumulators + split x, split W1, convert W2 ----------
__global__ void prep_kernel(const float* __restrict__ x, _Float16* __restrict__ xhi, _Float16* __restrict__ xlo,
                            const float* __restrict__ W1, _Float16* __restrict__ w1h, _Float16* __restrict__ w1l,
                            const float* __restrict__ W2, _Float16* __restrict__ w2h,
                            double* __restrict__ cs1, double* __restrict__ css1,
                            double* __restrict__ cs2, double* __restrict__ css2, int* __restrict__ scal) {
    int i = blockIdx.x * blockDim.x + threadIdx.x;
    int nth = gridDim.x * blockDim.x;
    for (int j = i; j < H1; j += nth) { cs1[j] = 0.0; css1[j] = 0.0; }
    for (int j = i; j < H2; j += nth) { cs2[j] = 0.0; css2[j] = 0.0; }
    if (i < 16) scal[i] = 0;
    const int nx = Nn * Ff / 4, nw1 = H1 * Ff / 4, nw2 = H2 * H1 / 4;
    for (int k = i; k < nx; k += nth) {
        float4 v = ((const float4*)x)[k];
        h4 H = { (_Float16)v.x, (_Float16)v.y, (_Float16)v.z, (_Float16)v.w };
        h4 L = { (_Float16)(v.x - (float)H[0]), (_Float16)(v.y - (float)H[1]),
                 (_Float16)(v.z - (float)H[2]), (_Float16)(v.w - (float)H[3]) };
        ((h4*)xhi)[k] = H;
        ((h4*)xlo)[k] = L;
    }
    for (int k = i; k < nw1; k += nth) {
        float4 v = ((const float4*)W1)[k];
        h4 H = { (_Float16)v.x, (_Float16)v.y, (_Float16)v.z, (_Float16)v.w };
        h4 L = { (_Float16)(v.x - (float)H[0]), (_Float16)(v.y - (float)H[1]),
                 (_Float16)(v.z - (float)H[2]), (_Float16)(v.w - (float)H[3]) };
        ((h4*)w1h)[k] = H;
        ((h4*)w1l)[k] = L;
    }
    for (int k = i; k < nw2; k += nth) {
        float4 v = ((const float4*)W2)[k];
        h4 H = { (_Float16)v.x, (_Float16)v.y, (_Float16)v.z, (_Float16)v.w };
        ((h4*)w2h)[k] = H;
    }
}

// ---------- GEMM1: 256x256 SPLIT tile, BK=32, 8 waves (2Mx4N, 128x64 each),
// 128 KB LDS double-buffer (all 4 operand arrays DMA-staged), ONE barrier per
// K-step, XCD-chunk + granule swizzle. C = Ahi*Bhi + Ahi*Blo + Alo*Bhi —
// per-element FP chain identical across tile variants -> bit-identical h.
// (Proven best of the 2-phase family: 232us.)
__global__ __launch_bounds__(512) void gemm1_256_kernel(
        const _Float16* __restrict__ Ahi, const _Float16* __restrict__ Alo,
        const _Float16* __restrict__ Bhi, const _Float16* __restrict__ Blo,
        const float* __restrict__ bias, float* __restrict__ C,
        double* __restrict__ csum, double* __restrict__ cssum)
{
    const int M = Nn;
    const int nwg = gridDim.x, orig = blockIdx.x;
    const int qq = nwg >> 3, rr = nwg & 7;
    const int xcd = orig & 7, idx = orig >> 3;
    const int lin = (xcd < rr ? xcd * (qq + 1) : rr * (qq + 1) + (xcd - rr) * qq) + idx;
    const int nT = H1 / 256;                   // 4
    const int bmI = lin / nT;
    const int bm = bmI * 256, bn = (lin - bmI * nT) * 256;
    __shared__ __align__(16) _Float16 smem[2][4][256 * 32];   // 128 KB
    const int tid = threadIdx.x, lane = tid & 63, wave = tid >> 6;   // 8 waves
    const int rIn = lane >> 2;
    const int kSrcByte = ((((lane & 3) - ((lane >> 3) & 3)) & 3) << 4);
    const int wr = wave >> 2, wc = wave & 3;   // wave grid 2(M) x 4(N)
    const int lr = lane & 15, kb = lane >> 4;
    const int pGr = ((kb + ((lr >> 1) & 3)) & 3) << 3;
    const int arr = wave >> 1;                 // 0=Ah 1=Al 2=Bh 3=Bl
    const int hv = wave & 1;                   // row half of the array
    const bool isA = (arr < 2);
    const _Float16* gp = (arr == 0) ? Ahi : (arr == 1) ? Alo : (arr == 2) ? Bhi : Blo;
    const int tb = isA ? bm : bn;
    f4 acc[8][4] = {};

    auto STAGE = [&](int b, int k0) {
        _Float16* lp = smem[b][arr] + hv * (128 * 32);
#pragma unroll
        for (int c = 0; c < 8; ++c) {
            int row = tb + hv * 128 + c * 16 + rIn;
            if (isA) row = min(row, M - 1);
            gl_lds16((const char*)gp + ((size_t)row * Ff + k0) * 2 + kSrcByte, lp + c * 512);
        }
    };

    int cur = 0;
    STAGE(0, 0);
    for (int k0 = 0; k0 < Ff; k0 += 32) {
        __syncthreads();
        if (k0 + 32 < Ff) STAGE(cur ^ 1, k0 + 32);
        const _Float16* AhP = smem[cur][0];
        const _Float16* AlP = smem[cur][1];
        const _Float16* BhP = smem[cur][2];
        const _Float16* BlP = smem[cur][3];
        h8 ahf[8], alf[8];
#pragma unroll
        for (int mi = 0; mi < 8; ++mi) {
            const int ar = (wr * 128 + mi * 16 + lr) * 32 + pGr;
            ahf[mi] = *(const h8*)&AhP[ar];
            alf[mi] = *(const h8*)&AlP[ar];
        }
#pragma unroll
        for (int ni = 0; ni < 4; ++ni) {
            const int br = (wc * 64 + ni * 16 + lr) * 32 + pGr;
            const h8 bh = *(const h8*)&BhP[br];
            const h8 bl = *(const h8*)&BlP[br];
#pragma unroll
            for (int mi = 0; mi < 8; ++mi) {
                acc[mi][ni] = __builtin_amdgcn_mfma_f32_16x16x32_f16(ahf[mi], bh, acc[mi][ni], 0, 0, 0);
                acc[mi][ni] = __builtin_amdgcn_mfma_f32_16x16x32_f16(ahf[mi], bl, acc[mi][ni], 0, 0, 0);
                acc[mi][ni] = __builtin_amdgcn_mfma_f32_16x16x32_f16(alf[mi], bh, acc[mi][ni], 0, 0, 0);
            }
        }
        cur ^= 1;
    }
    // epilogue: bias, store, fused column stats. C/D map: col=lane&15, row=(lane>>4)*4+reg
#pragma unroll
    for (int ni = 0; ni < 4; ++ni) {
        const int col = bn + wc * 64 + ni * 16 + lr;
        const float bv = bias[col];
        double sd_ = 0.0, ssd = 0.0;
#pragma unroll
        for (int mi = 0; mi < 8; ++mi)
#pragma unroll
            for (int r = 0; r < 4; ++r) {
                int row = bm + wr * 128 + mi * 16 + kb * 4 + r;
                if (row < M) {
                    float v = acc[mi][ni][r] + bv;
                    C[(size_t)row * H1 + col] = v;
                    sd_ += (double)v;
                    ssd += (double)v * (double)v;
                }
            }
        sd_ += __shfl_xor(sd_, 16); ssd += __shfl_xor(ssd, 16);
        sd_ += __shfl_xor(sd_, 32); ssd += __shfl_xor(ssd, 32);
        if (kb == 0) {
            atomicAdd(&csum[col], sd_);
            atomicAdd(&cssum[col], ssd);
        }
    }
}

// ---------- GEMM2: 128x128 non-split (round-7 proven schedule, dbuf LDS staging) ----------
__global__ __launch_bounds__(256) void gemm2_kernel(
        const _Float16* __restrict__ Ag, const _Float16* __restrict__ Bh,
        const float* __restrict__ bias, float* __restrict__ C,
        const int* __restrict__ Mptr, int nT,
        double* __restrict__ csum, double* __restrict__ cssum)
{
    const int M = Mptr[0];
    const int nwg = gridDim.x, orig = blockIdx.x;
    const int qq = nwg >> 3, rr = nwg & 7;
    const int xcd = orig & 7, idx = orig >> 3;
    const int lin = (xcd < rr ? xcd * (qq + 1) : rr * (qq + 1) + (xcd - rr) * qq) + idx;
    const int bmI = lin / nT;
    const int bm = bmI * 128, bn = (lin - bmI * nT) * 128;
    if (bm >= M) return;
    __shared__ __align__(16) _Float16 smem[2][2][128 * 32];
    const int tid = threadIdx.x, lane = tid & 63, wave = tid >> 6;
    const int rIn = lane >> 2;
    const int kSrcByte = ((((lane & 3) - ((lane >> 3) & 3)) & 3) << 4);
    const int wr = wave >> 1, wc = wave & 1;
    const int lr = lane & 15, kb = lane >> 4;
    const int pGr = ((kb + ((lr >> 1) & 3)) & 3) << 3;
    f4 acc[4][4] = {};

    auto STAGE = [&](int b, int k0) {
        const bool isA = (wave < 2);
        const _Float16* gp = isA ? Ag : Bh;
        _Float16* lp = smem[b][isA ? 0 : 1];
        const int tb = isA ? bm : bn;
        const int hf = wave & 1;
#pragma unroll
        for (int c2 = 0; c2 < 4; ++c2) {
            int c = hf * 4 + c2;
            int row = tb + c * 16 + rIn;
            if (isA) row = min(row, M - 1);
            gl_lds16((const char*)gp + ((size_t)row * H1 + k0) * 2 + kSrcByte, lp + c * 512);
        }
    };

    int cur = 0;
    STAGE(0, 0);
    for (int k0 = 0; k0 < H1; k0 += 32) {
        __syncthreads();
        if (k0 + 32 < H1) STAGE(cur ^ 1, k0 + 32);
        const _Float16* AhP = smem[cur][0];
        const _Float16* BhP = smem[cur][1];
        const int ar = (wr * 64 + lr) * 32 + pGr;
        const int br = (wc * 64 + lr) * 32 + pGr;
        h8 ahf[4], bhf[4];
#pragma unroll
        for (int i = 0; i < 4; ++i) {
            ahf[i] = *(const h8*)&AhP[ar + i * 512];
            bhf[i] = *(const h8*)&BhP[br + i * 512];
        }
#pragma unroll
        for (int mi = 0; mi < 4; ++mi)
#pragma unroll
            for (int ni = 0; ni < 4; ++ni)
                acc[mi][ni] = __builtin_amdgcn_mfma_f32_16x16x32_f16(ahf[mi], bhf[ni], acc[mi][ni], 0, 0, 0);
        cur ^= 1;
    }
#pragma unroll
    for (int ni = 0; ni < 4; ++ni) {
        const int col = bn + wc * 64 + ni * 16 + lr;
        const float bv = bias[col];
        double sd_ = 0.0, ssd = 0.0;
#pragma unroll
        for (int mi = 0; mi < 4; ++mi)
#pragma unroll
            for (int r = 0; r < 4; ++r) {
                int row = bm + wr * 64 + mi * 16 + kb * 4 + r;
                if (row < M) {
                    float v = acc[mi][ni][r] + bv;
                    C[(size_t)row * H2 + col] = v;
                    sd_ += (double)v;
                    ssd += (double)v * (double)v;
                }
            }
        sd_ += __shfl_xor(sd_, 16); ssd += __shfl_xor(ssd, 16);
        sd_ += __shfl_xor(sd_, 32); ssd += __shfl_xor(ssd, 32);
        if (kb == 0) {
            atomicAdd(&csum[col], sd_);
            atomicAdd(&cssum[col], ssd);
        }
    }
}

// ---------- BN1 params ----------
__global__ void bnparam_kernel(const double* __restrict__ s, const double* __restrict__ ss,
                               const float* __restrict__ g, const float* __restrict__ be,
                               float* __restrict__ a, float* __restrict__ bb, int cols) {
    int j = blockIdx.x * blockDim.x + threadIdx.x;
    if (j >= cols) return;
    double sum = s[j], sumsq = ss[j];
    double mean = sum / (double)Nn;
    double var = sumsq / (double)Nn - mean * mean;
    float aj = g[j] / sqrtf((float)var + EPSc);
    a[j] = aj;
    bb[j] = be[j] - (float)mean * aj;
}

// ---------- p,q row dots over BN+ReLU(h), no write-back; one WAVE per node ----------
__global__ __launch_bounds__(256) void pq_kernel(const float* __restrict__ h,
        const float* __restrict__ a, const float* __restrict__ bb,
        const float* __restrict__ Wp, float* __restrict__ p, float* __restrict__ q) {
    const int n = blockIdx.x * 4 + (threadIdx.x >> 6);
    if (n >= Nn) return;
    const int lane = threadIdx.x & 63;
    float sp = 0.f, sq = 0.f;
    const float* row = h + (size_t)n * H1;
#pragma unroll
    for (int u = 0; u < 4; ++u) {
        int j = u * 256 + lane * 4;
        float4 v = *(const float4*)(row + j);
        const float4 av = *(const float4*)(a + j);
        const float4 bv = *(const float4*)(bb + j);
        v.x = fmaxf(v.x * av.x + bv.x, 0.f);
        v.y = fmaxf(v.y * av.y + bv.y, 0.f);
        v.z = fmaxf(v.z * av.z + bv.z, 0.f);
        v.w = fmaxf(v.w * av.w + bv.w, 0.f);
        const float4 wp = *(const float4*)(Wp + j);
        const float4 wq = *(const float4*)(Wp + H1 + j);
        sp += v.x * wp.x + v.y * wp.y + v.z * wp.z + v.w * wp.w;
        sq += v.x * wq.x + v.y * wq.y + v.z * wq.z + v.w * wq.w;
    }
#pragma unroll
    for (int off = 32; off > 0; off >>= 1) {
        sp += __shfl_xor(sp, off);
        sq += __shfl_xor(sq, off);
    }
    if (lane == 0) { p[n] = sp; q[n] = sq; }
}

// ---------- fused edge-score + greedy matching, one block per graph ----------
// De-overlaid LDS (112KB) + ping-pong best[2]: round r bids into best[pb] while
// zeroing best[pb^1] during pass1 (different arrays) -> 2 barriers/round (was 3).
__global__ __launch_bounds__(1024) void match_fused_kernel(
        const int* __restrict__ ei,
        const float* __restrict__ p, const float* __restrict__ q,
        const float* __restrict__ bp,
        unsigned long long* __restrict__ packed,
        int* __restrict__ nodeA, int* __restrict__ nodeB,
        float* __restrict__ multc, int* __restrict__ scal,
        int* __restrict__ gbase, int* __restrict__ gcnt) {
    __shared__ float earr[EPg];                   // 32 KB
    __shared__ float pl[NPg], ql[NPg];            // 8 KB
    __shared__ unsigned maxu[NPg];                // 4 KB
    __shared__ unsigned long long den[NPg];       // 8 KB
    __shared__ unsigned short lst[2][EPg];        // 32 KB
    __shared__ unsigned long long best[2][NPg];   // 16 KB
    __shared__ int mergedS[NPg];                  // 4 KB
    __shared__ float lmult[NPg];                  // 4 KB
    __shared__ unsigned short lsA[NPg], ldA[NPg]; // 4 KB
    __shared__ int cnts[4];

    const int g = blockIdx.x;
    const int tid = threadIdx.x;
    const int e0 = g * EPg, n0 = g * NPg;
    const int* srcp = ei + e0;
    const int* dstp = ei + Ee + e0;
    const float bpv = bp[0];

    for (int i = tid; i < NPg; i += 1024) {
        pl[i] = p[n0 + i];
        ql[i] = q[n0 + i];
        maxu[i] = 0u;
        den[i] = 0ull;
        best[0][i] = 0ull;
        mergedS[i] = 0;
    }
    __syncthreads();
    // pass A: e + exact segment max
    for (int i = tid; i < EPg; i += 1024) {
        int s = srcp[i] - n0, d = dstp[i] - n0;
        float e = pl[s] + ql[d] + bpv;
        earr[i] = e;
        atomicMax(&maxu[d], fmap(e));
    }
    __syncthreads();
    // pass B: fixed-point denominator (deterministic)
    for (int i = tid; i < EPg; i += 1024) {
        int d = dstp[i] - n0;
        float ex = expf(earr[i] - funmap(maxu[d]));
        atomicAdd(&den[d], (unsigned long long)(ex * 4294967296.0f));
    }
    __syncthreads();
    // pass C: score -> packed u64 = score(31b)|inv_idx(13b)|s(10b)|d(10b)
    for (int i = tid; i < EPg; i += 1024) {
        int s = srcp[i] - n0, d = dstp[i] - n0;
        float ex = expf(earr[i] - funmap(maxu[d]));
        float den_f = (float)((double)den[d] * (1.0 / 4294967296.0));
        float sc = ex / den_f + 0.5f;
        packed[e0 + i] = ((unsigned long long)__float_as_uint(sc) << 33)
                       | ((unsigned long long)(8191u - (unsigned)i) << 20)
                       | ((unsigned long long)(unsigned)s << 10) | (unsigned long long)(unsigned)d;
        lst[0][i] = (unsigned short)i;
    }
    if (tid == 0) { cnts[0] = EPg; cnts[1] = 0; cnts[2] = 0; }
    __syncthreads();
    int cur = 0, pb = 0;
    for (int round = 0; round < 20000; ++round) {
        const int n_cur = cnts[cur];
        if (n_cur == 0) break;
        if (tid == 0) cnts[cur ^ 1] = 0;
        // pass 1: drop dead edges + locally-dominant bid; zero other best concurrently
        for (int i = tid; i < NPg; i += 1024) best[pb ^ 1][i] = 0ull;
        for (int ii = tid; ii < n_cur; ii += 1024) {
            int le = lst[cur][ii];
            unsigned long long pk = packed[e0 + le];
            int s = (int)((pk >> 10) & 1023), d = (int)(pk & 1023);
            if (mergedS[s] | mergedS[d]) { lst[cur][ii] = 0xFFFF; continue; }
            atomicMax(&best[pb][s], pk);
            atomicMax(&best[pb][d], pk);
        }
        __syncthreads();
        // pass 2: winners merge; losers carry
        for (int ii = tid; ii < n_cur; ii += 1024) {
            int le = lst[cur][ii];
            if (le == 0xFFFF) continue;
            unsigned long long pk = packed[e0 + le];
            int s = (int)((pk >> 10) & 1023), d = (int)(pk & 1023);
            if (best[pb][s] == pk && best[pb][d] == pk) {
                int c = atomicAdd(&cnts[2], 1);
                lsA[c] = (unsigned short)s;
                ldA[c] = (s == d) ? (unsigned short)0xFFFF : (unsigned short)d;
                lmult[c] = __uint_as_float((unsigned)(pk >> 33));
                mergedS[s] = 1;
                if (d != s) mergedS[d] = 1;
            } else {
                int pos = atomicAdd(&cnts[cur ^ 1], 1);
                lst[cur ^ 1][pos] = (unsigned short)le;
            }
        }
        __syncthreads();
        cur ^= 1;
        pb ^= 1;
    }
    // singletons
    for (int i = tid; i < NPg; i += 1024) {
        if (!mergedS[i]) {
            int c = atomicAdd(&cnts[2], 1);
            lsA[c] = (unsigned short)i;
            ldA[c] = 0xFFFF;
            lmult[c] = 1.0f;
        }
    }
    __syncthreads();
    if (tid == 0) {
        int ncl = cnts[2];
        int base = atomicAdd(&scal[2], ncl);
        cnts[3] = base;
        gbase[g] = base;
        gcnt[g] = ncl;
    }
    __syncthreads();
    const int ncl = cnts[2], base = cnts[3];
    for (int i = tid; i < ncl; i += 1024) {
        nodeA[base + i] = n0 + (int)lsA[i];
        nodeB[base + i] = (ldA[i] == 0xFFFF) ? -1 : (n0 + (int)ldA[i]);
        multc[base + i] = lmult[i];
    }
}

// ---------- gather clustered rows: Ag[c] = f16(mult*(relu(bn(h[a]))+relu(bn(h[b])))) ----------
__global__ __launch_bounds__(256) void gather_kernel(const float* __restrict__ h,
        const float* __restrict__ a, const float* __restrict__ bb,
        const int* __restrict__ nodeA, const int* __restrict__ nodeB,
        const float* __restrict__ multc, const int* __restrict__ scal,
        _Float16* __restrict__ Ag) {
    int c = blockIdx.x * 4 + (threadIdx.x >> 6);
    if (c >= scal[2]) return;
    const int lane = threadIdx.x & 63;
    int na = nodeA[c], nb = nodeB[c];
    float mu = multc[c];
#pragma unroll
    for (int u = 0; u < 4; ++u) {
        int j = u * 256 + lane * 4;
        const float4 av = *(const float4*)(a + j);
        const float4 bv = *(const float4*)(bb + j);
        float4 v = *(const float4*)(h + (size_t)na * H1 + j);
        v.x = fmaxf(v.x * av.x + bv.x, 0.f);
        v.y = fmaxf(v.y * av.y + bv.y, 0.f);
        v.z = fmaxf(v.z * av.z + bv.z, 0.f);
        v.w = fmaxf(v.w * av.w + bv.w, 0.f);
        if (nb >= 0) {
            float4 w = *(const float4*)(h + (size_t)nb * H1 + j);
            v.x += fmaxf(w.x * av.x + bv.x, 0.f);
            v.y += fmaxf(w.y * av.y + bv.y, 0.f);
            v.z += fmaxf(w.z * av.z + bv.z, 0.f);
            v.w += fmaxf(w.w * av.w + bv.w, 0.f);
        }
        h4 o = { (_Float16)(mu * v.x), (_Float16)(mu * v.y), (_Float16)(mu * v.z), (_Float16)(mu * v.w) };
        *(h4*)(Ag + (size_t)c * H1 + j) = o;
    }
}

// ---------- pool: BN2 params computed inline (identical math to bnparam) + seg sum ----------
__global__ __launch_bounds__(256) void pool_seg_kernel(const float* __restrict__ C2,
        const double* __restrict__ cs2, const double* __restrict__ css2,
        const float* __restrict__ g2, const float* __restrict__ be2, const float* __restrict__ b2,
        const int* __restrict__ CvPtr,
        const int* __restrict__ gbase, const int* __restrict__ gcnt,
        float* __restrict__ pool) {
    const int g = blockIdx.x;
    const int j = blockIdx.y * 256 + threadIdx.x;
    double sum = cs2[j], sumsq = css2[j];
    double pad = (double)(Nn - CvPtr[0]);
    double bv = (double)b2[j];
    sum += pad * bv; sumsq += pad * bv * bv;
    double mean = sum / (double)Nn;
    double var = sumsq / (double)Nn - mean * mean;
    float aj = g2[j] / sqrtf((float)var + EPSc);
    float bj = be2[j] - (float)mean * aj;
    const int b0 = gbase[g], cN = gcnt[g];
    float s = 0.f;
    for (int c = b0; c < b0 + cN; ++c)
        s += fmaxf(C2[(size_t)c * H2 + j] * aj + bj, 0.f);
    pool[g * H2 + j] = s;
}

// ---------- fused FC1+FC2: block g computes hid[g] in LDS then out[g] ----------
__global__ __launch_bounds__(256) void fc_kernel(const float* __restrict__ pool,
        const int* __restrict__ gcnt,
        const float* __restrict__ Wfc, const float* __restrict__ bfc,
        const float* __restrict__ Wfc1, const float* __restrict__ bfc1,
        float* __restrict__ out) {
    __shared__ float hidS[200];
    const int g = blockIdx.x;
    const int o = threadIdx.x;
    float inv = 1.0f / fmaxf((float)gcnt[g], 1.0f);
    if (o < 200) {
        float s = 0.f;
        for (int j = 0; j < H2; ++j) s += (pool[g * H2 + j] * inv) * Wfc[o * H2 + j];
        hidS[o] = fmaxf(s + bfc[o], 0.f);
    }
    __syncthreads();
    if (o < OUTd) {
        float s = bfc1[o];
        for (int t = 0; t < 200; ++t) s += hidS[t] * Wfc1[o * 200 + t];
        out[g * OUTd + o] = s;
    }
}

extern "C" void kernel_launch(void* const* d_in, const int* in_sizes, int n_in,
                              void* d_out, int out_size, void* d_ws, size_t ws_size,
                              hipStream_t stream) {
    (void)in_sizes; (void)n_in; (void)out_size; (void)ws_size;
    const float* x    = (const float*)d_in[0];
    const int*   ei   = (const int*)d_in[1];
    const float* W1   = (const float*)d_in[3];
    const float* b1   = (const float*)d_in[4];
    const float* g1   = (const float*)d_in[5];
    const float* be1  = (const float*)d_in[6];
    const float* Wp   = (const float*)d_in[7];
    const float* bp   = (const float*)d_in[8];
    const float* W2   = (const float*)d_in[9];
    const float* b2   = (const float*)d_in[10];
    const float* g2   = (const float*)d_in[11];
    const float* be2  = (const float*)d_in[12];
    const float* Wfc  = (const float*)d_in[13];
    const float* bfc  = (const float*)d_in[14];
    const float* Wfc1 = (const float*)d_in[15];
    const float* bfc1 = (const float*)d_in[16];

    char* w = (char*)d_ws;
    auto take = [&](size_t bytes) -> char* {
        char* r = w;
        w += (bytes + 255) & ~(size_t)255;
        return r;
    };
    // R1: h (f32) -> reused as gemm2 output C2 after gather
    float* h      = (float*)take((size_t)Nn * H1 * 4);          // 204.8 MB
    // R2: xhi|xlo -> reused as Ag (f16 gathered rows) after matching
    _Float16* xhi = (_Float16*)take((size_t)Nn * Ff * 2);       // 51.2 MB
    _Float16* xlo = (_Float16*)take((size_t)Nn * Ff * 2);       // 51.2 MB
    _Float16* w1h = (_Float16*)take((size_t)H1 * Ff * 2);
    _Float16* w1l = (_Float16*)take((size_t)H1 * Ff * 2);
    _Float16* w2h = (_Float16*)take((size_t)H2 * H1 * 2);
    float* p      = (float*)take((size_t)Nn * 4);
    float* q      = (float*)take((size_t)Nn * 4);
    unsigned long long* packed = (unsigned long long*)take((size_t)Ee * 8);
    int* nodeA    = (int*)take((size_t)Nn * 4);
    int* nodeB    = (int*)take((size_t)Nn * 4);
    float* multc  = (float*)take((size_t)Nn * 4);
    double* cs1   = (double*)take((size_t)H1 * 8);
    double* css1  = (double*)take((size_t)H1 * 8);
    double* cs2   = (double*)take((size_t)H2 * 8);
    double* css2  = (double*)take((size_t)H2 * 8);
    float* a1     = (float*)take((size_t)H1 * 4);
    float* bb1    = (float*)take((size_t)H1 * 4);
    float* pool   = (float*)take((size_t)Bb * H2 * 4);
    int* scal     = (int*)take(64 * 4);
    int* gbase    = (int*)take(64 * 4);
    int* gcnt     = (int*)take(64 * 4);
    _Float16* Ag  = xhi;   // alias after gemm1
    float* C2o    = h;     // alias after gather

    const int mT  = (Nn + 127) / 128;   // 391 (gemm2)
    const int mT2 = (Nn + 255) / 256;   // 196 (gemm1 256^2)

    prep_kernel<<<dim3(2048), dim3(256), 0, stream>>>(x, xhi, xlo, W1, w1h, w1l, W2, w2h,
                                                      cs1, css1, cs2, css2, scal);
    gemm1_256_kernel<<<dim3(mT2 * (H1 / 256)), dim3(512), 0, stream>>>(
        xhi, xlo, w1h, w1l, b1, h, cs1, css1);
    bnparam_kernel<<<dim3((H1 + 255) / 256), dim3(256), 0, stream>>>(cs1, css1, g1, be1, a1, bb1, H1);
    pq_kernel<<<dim3((Nn + 3) / 4), dim3(256), 0, stream>>>(h, a1, bb1, Wp, p, q);
    match_fused_kernel<<<dim3(Bb), dim3(1024), 0, stream>>>(ei, p, q, bp, packed,
        nodeA, nodeB, multc, scal, gbase, gcnt);
    gather_kernel<<<dim3((Nn + 3) / 4), dim3(256), 0, stream>>>(h, a1, bb1, nodeA, nodeB, multc, scal, Ag);
    gemm2_kernel<<<dim3(mT * (H2 / 128)), dim3(256), 0, stream>>>(
        Ag, w2h, b2, C2o, scal + 2, H2 / 128, cs2, css2);
    pool_seg_kernel<<<dim3(Bb, H2 / 256), dim3(256), 0, stream>>>(
        C2o, cs2, css2, g2, be2, b2, scal + 2, gbase, gcnt, pool);
    fc_kernel<<<dim3(Bb), dim3(256), 0, stream>>>(pool, gcnt, Wfc, bfc, Wfc1, bfc1, (float*)d_out);
}